// Round 5
// baseline (2115.602 us; speedup 1.0000x reference)
//
#include <hip/hip_runtime.h>

#define NN 50000
#define NE 800000

typedef unsigned int  u32;
typedef unsigned short u16;
typedef __attribute__((ext_vector_type(8))) short short8;
typedef __attribute__((ext_vector_type(4))) float f32x4;

union ABfrag { uint2 u2[2]; uint4 u4; short8 s8; };

__device__ __forceinline__ float silu_f(float v) {
    return v * (1.0f / (1.0f + __expf(-v)));
}
__device__ __forceinline__ u32 bfr(float x) {   // f32 -> bf16 (RNE), low 16 bits
    u32 u = __float_as_uint(x);
    u += 0x7fffu + ((u >> 16) & 1u);
    return u >> 16;
}
__device__ __forceinline__ float bff(u32 h) { return __uint_as_float(h << 16); }

// ---------------- embedding: h64 = h @ emb_w + emb_b  (N x 16 -> N x 64)
__global__ __launch_bounds__(256, 4) void k_embed(const float* __restrict__ h,
        const float* __restrict__ w, const float* __restrict__ b,
        float* __restrict__ h64) {
    int n = blockIdx.x * 256 + threadIdx.x;
    if (n >= NN) return;
    const float4* h4 = (const float4*)(h + (long)n * 16);
    float in[16];
    #pragma unroll
    for (int c = 0; c < 4; ++c) {
        float4 v = h4[c];
        in[4*c+0] = v.x; in[4*c+1] = v.y; in[4*c+2] = v.z; in[4*c+3] = v.w;
    }
    float acc[64];
    #pragma unroll
    for (int j = 0; j < 64; ++j) acc[j] = b[j];
    #pragma unroll
    for (int k = 0; k < 16; ++k) {
        #pragma unroll
        for (int j = 0; j < 64; ++j) acc[j] = fmaf(in[k], w[k*64 + j], acc[j]);
    }
    float4* o4 = (float4*)(h64 + (long)n * 64);
    #pragma unroll
    for (int c = 0; c < 16; ++c)
        o4[c] = make_float4(acc[4*c+0], acc[4*c+1], acc[4*c+2], acc[4*c+3]);
}

// ---------------- CSR-order build: histogram / scan / scatter ----------------
__global__ __launch_bounds__(256, 4) void k_hist(const int* __restrict__ row,
        int* __restrict__ deg) {
    int e = blockIdx.x * 256 + threadIdx.x;
    if (e < NE) atomicAdd(&deg[row[e]], 1);
}

__global__ __launch_bounds__(256) void k_scan(const int* __restrict__ deg,
        int* __restrict__ base) {
    __shared__ int s[256];
    const int CH = (NN + 255) / 256;
    int t = threadIdx.x;
    int lo = t * CH, hi = min(lo + CH, NN);
    int sum = 0;
    for (int i = lo; i < hi; ++i) sum += deg[i];
    s[t] = sum;
    __syncthreads();
    #pragma unroll
    for (int d = 1; d < 256; d <<= 1) {
        int v = (t >= d) ? s[t - d] : 0;
        __syncthreads();
        s[t] += v;
        __syncthreads();
    }
    int run = s[t] - sum;
    for (int i = lo; i < hi; ++i) { base[i] = run; run += deg[i]; }
}

__global__ __launch_bounds__(256, 4) void k_scatter(const int* __restrict__ row,
        const int* __restrict__ col, int* __restrict__ base,
        int* __restrict__ rowS, int* __restrict__ colS) {
    int e = blockIdx.x * 256 + threadIdx.x;
    if (e >= NE) return;
    int r = row[e];
    int p = atomicAdd(&base[r], 1);
    rowS[p] = r;
    colS[p] = col[e];
}

// ---------------- per-edge squared distance (sorted edge space)
__global__ __launch_bounds__(256, 4) void k_radial(const float* __restrict__ x,
        const int* __restrict__ rowS, const int* __restrict__ colS,
        float* __restrict__ radial) {
    int e = blockIdx.x * 256 + threadIdx.x;
    if (e >= NE) return;
    int r = rowS[e], c = colS[e];
    float dx = x[r*3+0] - x[c*3+0];
    float dy = x[r*3+1] - x[c*3+1];
    float dz = x[r*3+2] - x[c*3+2];
    radial[e] = dx*dx + dy*dy + dz*dz;
}

// ---------------- w2 -> bf16 B-fragment order, 6 layers (4 edge + 2 coord)
__global__ __launch_bounds__(256, 4) void k_wconv(const float* __restrict__ e_w2,
        const float* __restrict__ q_w2, u16* __restrict__ w2f) {
    int t = blockIdx.x * 256 + threadIdx.x;
    if (t >= 6 * 4096) return;
    int L = t >> 12, rL = t & 4095;
    int j = rL & 7, lane = (rL >> 3) & 63, ns = rL >> 9;
    int n = ns >> 1, s = ns & 1;
    int k = 8 * (lane >> 4) + j + 32 * s;
    int colj = 16 * n + (lane & 15);
    const float* src = (L < 4) ? (e_w2 + (size_t)L * 4096)
                               : (q_w2 + (size_t)(L - 4) * 4096);
    w2f[t] = (u16)bfr(src[k * 64 + colj]);
}

// ---------------- P/Q: wave-uniform output quarter; bf16-packed output
__global__ __launch_bounds__(256, 4) void k_pq(const float* __restrict__ h64,
        const float* __restrict__ w1, const float* __restrict__ b1,
        u32* __restrict__ Pb, u32* __restrict__ Qb) {
    int w = threadIdx.x >> 6, lane = threadIdx.x & 63;
    int n = blockIdx.x * 64 + lane;
    if (n >= NN) return;
    const float4* in4 = (const float4*)(h64 + (size_t)n * 64);
    float accP[16], accQ[16];
    #pragma unroll
    for (int j = 0; j < 16; ++j) { accP[j] = b1[16*w + j]; accQ[j] = 0.0f; }
    const float* w1b = w1 + 64 * 64;
    #pragma unroll
    for (int c = 0; c < 16; ++c) {
        float4 f = in4[c];
        float vv[4] = {f.x, f.y, f.z, f.w};
        #pragma unroll
        for (int u = 0; u < 4; ++u) {
            int k = 4*c + u;
            #pragma unroll
            for (int j = 0; j < 16; ++j) {
                accP[j] = fmaf(vv[u], w1 [k*64 + 16*w + j], accP[j]);
                accQ[j] = fmaf(vv[u], w1b[k*64 + 16*w + j], accQ[j]);
            }
        }
    }
    u32 po[8], qo[8];
    #pragma unroll
    for (int c = 0; c < 8; ++c) {
        po[c] = bfr(accP[2*c]) | (bfr(accP[2*c+1]) << 16);
        qo[c] = bfr(accQ[2*c]) | (bfr(accQ[2*c+1]) << 16);
    }
    uint4* pp = (uint4*)(Pb + (size_t)n*32 + 8*w);
    uint4* qp = (uint4*)(Qb + (size_t)n*32 + 8*w);
    pp[0] = make_uint4(po[0], po[1], po[2], po[3]);
    pp[1] = make_uint4(po[4], po[5], po[6], po[7]);
    qp[0] = make_uint4(qo[0], qo[1], qo[2], qo[3]);
    qp[1] = make_uint4(qo[4], qo[5], qo[6], qo[7]);
}

// ---------------- edge MLP: layer1 per-thread (bf16 P/Q), layer2 MFMA,
// M_lds overlaid on A_lds (per-wave union) -> 4 blocks/CU
__global__ __launch_bounds__(256, 4) void k_edge(
        const u32* __restrict__ Pb, const u32* __restrict__ Qb,
        const float* __restrict__ radial, const float* __restrict__ dist0,
        const int* __restrict__ rowS, const int* __restrict__ colS,
        const float* __restrict__ w1t,   // rows 128,129 of w1: [2][64]
        const u16* __restrict__ w2f,
        const float* __restrict__ b2,
        float* __restrict__ agg) {
    __shared__ u16 S_lds[4][4224];   // union: A [64][64] (8192B) / M [64f][66e] (8448B)
    int tid = threadIdx.x;
    int w = tid >> 6, lane = tid & 63;
    int e = blockIdx.x * 256 + w * 64 + lane;   // NE % 256 == 0
    u16* Aw = S_lds[w];
    int r = rowS[e], c = colS[e];
    float rad = radial[e], d0 = dist0[e];
    const uint2* Pr = (const uint2*)(Pb + (size_t)r * 32);
    const uint2* Qc = (const uint2*)(Qb + (size_t)c * 32);
    int swz = (lane & 15) << 3;
    #pragma unroll
    for (int kc = 0; kc < 16; ++kc) {
        uint2 pu = Pr[kc], qu = Qc[kc];
        float p0 = bff(pu.x & 0xffffu), p1 = bff(pu.x >> 16);
        float p2 = bff(pu.y & 0xffffu), p3 = bff(pu.y >> 16);
        float q0 = bff(qu.x & 0xffffu), q1 = bff(qu.x >> 16);
        float q2 = bff(qu.y & 0xffffu), q3 = bff(qu.y >> 16);
        float h0 = silu_f(p0 + q0 + rad*w1t[4*kc+0] + d0*w1t[64+4*kc+0]);
        float h1 = silu_f(p1 + q1 + rad*w1t[4*kc+1] + d0*w1t[64+4*kc+1]);
        float h2 = silu_f(p2 + q2 + rad*w1t[4*kc+2] + d0*w1t[64+4*kc+2]);
        float h3 = silu_f(p3 + q3 + rad*w1t[4*kc+3] + d0*w1t[64+4*kc+3]);
        uint2 pk = make_uint2(bfr(h0) | (bfr(h1) << 16), bfr(h2) | (bfr(h3) << 16));
        *(uint2*)((char*)Aw + lane*128 + ((8*kc) ^ swz)) = pk;
    }
    __syncthreads();
    ABfrag bf[4][2];
    #pragma unroll
    for (int n = 0; n < 4; ++n)
        #pragma unroll
        for (int s = 0; s < 2; ++s)
            bf[n][s].u4 = *(const uint4*)(w2f + ((n*2 + s)*64 + lane)*8);
    int r0 = lane & 15, g = lane >> 4;
    f32x4 acc[4][4];
    #pragma unroll
    for (int t = 0; t < 4; ++t)
        #pragma unroll
        for (int n = 0; n < 4; ++n)
            acc[t][n] = (f32x4){0.f, 0.f, 0.f, 0.f};
    #pragma unroll
    for (int t = 0; t < 4; ++t) {
        #pragma unroll
        for (int s = 0; s < 2; ++s) {
            int boff = 16*g + 64*s;
            ABfrag af;
            af.u2[0] = *(uint2*)((char*)Aw + (16*t + r0)*128 + ( boff      ^ (r0 << 3)));
            af.u2[1] = *(uint2*)((char*)Aw + (16*t + r0)*128 + ((boff + 8) ^ (r0 << 3)));
            #pragma unroll
            for (int n = 0; n < 4; ++n)
                acc[t][n] = __builtin_amdgcn_mfma_f32_16x16x32_bf16(
                    af.s8, bf[n][s].s8, acc[t][n], 0, 0, 0);
        }
    }
    __syncthreads();   // all A reads complete before the M overlay writes
    u16* Mw = Aw;      // overlay: [64 feat][66 edge] bf16, row stride 132 B
    #pragma unroll
    for (int n = 0; n < 4; ++n) {
        float b2v = b2[16*n + r0];
        #pragma unroll
        for (int t = 0; t < 4; ++t) {
            f32x4 z = acc[t][n];
            u32 p0 = bfr(silu_f(z[0] + b2v)) | (bfr(silu_f(z[1] + b2v)) << 16);
            u32 p1 = bfr(silu_f(z[2] + b2v)) | (bfr(silu_f(z[3] + b2v)) << 16);
            *(uint2*)((char*)Mw + (16*n + r0)*132 + 32*t + 8*g) = make_uint2(p0, p1);
        }
    }
    __syncthreads();
    // aggregation: lane = feature; walk 64 sorted edges, flush per run (coalesced)
    float racc = 0.0f;
    int cur = __builtin_amdgcn_readfirstlane(__shfl(r, 0));
    #pragma unroll
    for (int ch = 0; ch < 16; ++ch) {
        uint2 mm = *(uint2*)((char*)Mw + lane*132 + 8*ch);
        #pragma unroll
        for (int q = 0; q < 4; ++q) {
            int ee = 4*ch + q;
            u32 hu = ((q & 2) ? mm.y : mm.x) >> ((q & 1) * 16);
            float v = bff(hu & 0xffffu);
            int rr = __builtin_amdgcn_readfirstlane(__shfl(r, ee));
            if (rr != cur) {
                atomicAdd(&agg[(long)cur*64 + lane], racc);
                racc = 0.0f; cur = rr;
            }
            racc += v;
        }
    }
    atomicAdd(&agg[(long)cur*64 + lane], racc);
}

// ---------------- node MLP: 4 waves per 64-node tile, wave = output quarter.
// Weights wave-uniform (s_load); inputs staged once in LDS fp32.
__global__ __launch_bounds__(256, 3) void k_node(float* __restrict__ h64,
        const float* __restrict__ agg,
        const float* __restrict__ w1, const float* __restrict__ b1,
        const float* __restrict__ w2, const float* __restrict__ b2) {
    __shared__ float X [64][132];   // [node][ h(0..63) | agg*0.01(64..127) ], pad 4
    __shared__ float Hd[64][68];    // silu(hidden), pad 4
    int t = threadIdx.x;
    int q = t >> 6, lane = t & 63;
    int nb0 = blockIdx.x * 64;
    // cooperative stage: 64 rows x 32 float4
    #pragma unroll
    for (int i = 0; i < 8; ++i) {
        int idx = i * 256 + t;
        int r = idx >> 5, c = idx & 31;
        int n = nb0 + r;
        if (n < NN) {
            float4 v;
            if (c < 16) {
                v = ((const float4*)(h64 + (size_t)n * 64))[c];
            } else {
                float4 a = ((const float4*)(agg + (size_t)n * 64))[c - 16];
                v = make_float4(a.x*0.01f, a.y*0.01f, a.z*0.01f, a.w*0.01f);
            }
            *(float4*)&X[r][4*c] = v;
        }
    }
    __syncthreads();
    float acc[16];
    #pragma unroll
    for (int j = 0; j < 16; ++j) acc[j] = b1[16*q + j];
    #pragma unroll
    for (int c = 0; c < 32; ++c) {
        float4 xv = *(const float4*)&X[lane][4*c];
        float vv[4] = {xv.x, xv.y, xv.z, xv.w};
        #pragma unroll
        for (int u = 0; u < 4; ++u) {
            int k = 4*c + u;
            #pragma unroll
            for (int j = 0; j < 16; ++j)
                acc[j] = fmaf(vv[u], w1[k*64 + 16*q + j], acc[j]);
        }
    }
    #pragma unroll
    for (int j = 0; j < 16; ++j) Hd[lane][16*q + j] = silu_f(acc[j]);
    __syncthreads();
    float acc2[16];
    #pragma unroll
    for (int j = 0; j < 16; ++j) acc2[j] = b2[16*q + j];
    #pragma unroll
    for (int c = 0; c < 16; ++c) {
        float4 hv = *(const float4*)&Hd[lane][4*c];
        float vv[4] = {hv.x, hv.y, hv.z, hv.w};
        #pragma unroll
        for (int u = 0; u < 4; ++u) {
            int k = 4*c + u;
            #pragma unroll
            for (int j = 0; j < 16; ++j)
                acc2[j] = fmaf(vv[u], w2[k*64 + 16*q + j], acc2[j]);
        }
    }
    // residual (fp32, from LDS) + write back into X, then coalesced store
    #pragma unroll
    for (int j = 0; j < 16; ++j) acc2[j] += X[lane][16*q + j];
    #pragma unroll
    for (int j = 0; j < 16; ++j) X[lane][16*q + j] = acc2[j];
    __syncthreads();
    #pragma unroll
    for (int i = 0; i < 4; ++i) {
        int idx = i * 256 + t;
        int r = idx >> 4, c = idx & 15;
        int n = nb0 + r;
        if (n < NN)
            ((float4*)(h64 + (size_t)n * 64))[c] = *(const float4*)&X[r][4*c];
    }
}

// ---------------- coordinate update: layer2 via MFMA, phi via shfl butterfly
__global__ __launch_bounds__(256, 4) void k_coord(
        const u32* __restrict__ Pb, const u32* __restrict__ Qb,
        const float* __restrict__ radial, const float* __restrict__ dist0,
        const int* __restrict__ rowS, const int* __restrict__ colS,
        const float* __restrict__ w1t, const u16* __restrict__ w2f,
        const float* __restrict__ b2, const float* __restrict__ w3,
        const float* __restrict__ x_old, float* __restrict__ x_new) {
    __shared__ u16 A_lds[4][4096];
    int tid = threadIdx.x;
    int w = tid >> 6, lane = tid & 63;
    int e = blockIdx.x * 256 + w * 64 + lane;
    u16* Aw = A_lds[w];
    int r = rowS[e], c = colS[e];
    float rad = radial[e], d0 = dist0[e];
    const uint2* Pr = (const uint2*)(Pb + (size_t)r * 32);
    const uint2* Qc = (const uint2*)(Qb + (size_t)c * 32);
    int swz = (lane & 15) << 3;
    #pragma unroll
    for (int kc = 0; kc < 16; ++kc) {
        uint2 pu = Pr[kc], qu = Qc[kc];
        float p0 = bff(pu.x & 0xffffu), p1 = bff(pu.x >> 16);
        float p2 = bff(pu.y & 0xffffu), p3 = bff(pu.y >> 16);
        float q0 = bff(qu.x & 0xffffu), q1 = bff(qu.x >> 16);
        float q2 = bff(qu.y & 0xffffu), q3 = bff(qu.y >> 16);
        float h0 = silu_f(p0 + q0 + rad*w1t[4*kc+0] + d0*w1t[64+4*kc+0]);
        float h1 = silu_f(p1 + q1 + rad*w1t[4*kc+1] + d0*w1t[64+4*kc+1]);
        float h2 = silu_f(p2 + q2 + rad*w1t[4*kc+2] + d0*w1t[64+4*kc+2]);
        float h3 = silu_f(p3 + q3 + rad*w1t[4*kc+3] + d0*w1t[64+4*kc+3]);
        uint2 pk = make_uint2(bfr(h0) | (bfr(h1) << 16), bfr(h2) | (bfr(h3) << 16));
        *(uint2*)((char*)Aw + lane*128 + ((8*kc) ^ swz)) = pk;
    }
    __syncthreads();
    ABfrag bf[4][2];
    #pragma unroll
    for (int n = 0; n < 4; ++n)
        #pragma unroll
        for (int s = 0; s < 2; ++s)
            bf[n][s].u4 = *(const uint4*)(w2f + ((n*2 + s)*64 + lane)*8);
    int r0 = lane & 15, g = lane >> 4;
    f32x4 acc[4][4];
    #pragma unroll
    for (int t = 0; t < 4; ++t)
        #pragma unroll
        for (int n = 0; n < 4; ++n)
            acc[t][n] = (f32x4){0.f, 0.f, 0.f, 0.f};
    #pragma unroll
    for (int t = 0; t < 4; ++t) {
        #pragma unroll
        for (int s = 0; s < 2; ++s) {
            int boff = 16*g + 64*s;
            ABfrag af;
            af.u2[0] = *(uint2*)((char*)Aw + (16*t + r0)*128 + ( boff      ^ (r0 << 3)));
            af.u2[1] = *(uint2*)((char*)Aw + (16*t + r0)*128 + ((boff + 8) ^ (r0 << 3)));
            #pragma unroll
            for (int n = 0; n < 4; ++n)
                acc[t][n] = __builtin_amdgcn_mfma_f32_16x16x32_bf16(
                    af.s8, bf[n][s].s8, acc[t][n], 0, 0, 0);
        }
    }
    float w3v[4], b2v[4];
    #pragma unroll
    for (int n = 0; n < 4; ++n) { w3v[n] = w3[16*n + r0]; b2v[n] = b2[16*n + r0]; }
    float ph[16];
    #pragma unroll
    for (int t = 0; t < 4; ++t)
        #pragma unroll
        for (int q = 0; q < 4; ++q) {
            float s = 0.f;
            #pragma unroll
            for (int n = 0; n < 4; ++n)
                s = fmaf(silu_f(acc[t][n][q] + b2v[n]), w3v[n], s);
            ph[t*4 + q] = s;
        }
    #pragma unroll
    for (int d = 1; d < 16; d <<= 1)
        #pragma unroll
        for (int i = 0; i < 16; ++i) ph[i] += __shfl_xor(ph[i], d);
    __syncthreads();
    float* phl = (float*)Aw;
    if (r0 == 0) {
        #pragma unroll
        for (int t = 0; t < 4; ++t)
            #pragma unroll
            for (int q = 0; q < 4; ++q)
                phl[16*t + 4*g + q] = ph[t*4 + q];
    }
    __syncthreads();
    float phi = phl[lane] * 0.01f;
    float dx = x_old[r*3+0] - x_old[c*3+0];
    float dy = x_old[r*3+1] - x_old[c*3+1];
    float dz = x_old[r*3+2] - x_old[c*3+2];
    float inv = phi / (sqrtf(rad + 1e-8f) + 1.0f);
    float tx = dx * inv, ty = dy * inv, tz = dz * inv;
    int rprev = __shfl_up(r, 1);
    bool head = (lane == 0) || (rprev != r);
    unsigned long long hm = __ballot(head);
    int runid = __popcll(hm & ((2ull << lane) - 1ull));
    #pragma unroll
    for (int d = 1; d < 64; d <<= 1) {
        float ox = __shfl_up(tx, d);
        float oy = __shfl_up(ty, d);
        float oz = __shfl_up(tz, d);
        int orid = __shfl_up(runid, d);
        if (lane >= d && orid == runid) { tx += ox; ty += oy; tz += oz; }
    }
    int rid_next = __shfl_down(runid, 1);
    bool tail = (lane == 63) || (rid_next != runid);
    if (tail) {
        atomicAdd(&x_new[r*3+0], tx);
        atomicAdd(&x_new[r*3+1], ty);
        atomicAdd(&x_new[r*3+2], tz);
    }
}

// ---------------- output projection: out = h64 @ out_w + out_b
__global__ __launch_bounds__(256, 4) void k_out(const float* __restrict__ h64,
        const float* __restrict__ w, const float* __restrict__ b,
        float* __restrict__ out) {
    int n = blockIdx.x * 256 + threadIdx.x;
    if (n >= NN) return;
    float acc[16];
    #pragma unroll
    for (int j = 0; j < 16; ++j) acc[j] = b[j];
    const float4* h4 = (const float4*)(h64 + (long)n*64);
    #pragma unroll
    for (int c = 0; c < 16; ++c) {
        float4 v = h4[c];
        float vv[4] = {v.x, v.y, v.z, v.w};
        #pragma unroll
        for (int t = 0; t < 4; ++t) {
            #pragma unroll
            for (int j = 0; j < 16; ++j)
                acc[j] = fmaf(vv[t], w[(4*c+t)*16 + j], acc[j]);
        }
    }
    float4* o4 = (float4*)(out + (long)n*16);
    #pragma unroll
    for (int cq = 0; cq < 4; ++cq)
        o4[cq] = make_float4(acc[4*cq+0],acc[4*cq+1],acc[4*cq+2],acc[4*cq+3]);
}

extern "C" void kernel_launch(void* const* d_in, const int* in_sizes, int n_in,
                              void* d_out, int out_size, void* d_ws, size_t ws_size,
                              hipStream_t stream) {
    const float* h_in  = (const float*)d_in[0];
    const float* x_in  = (const float*)d_in[1];
    const int*   row   = (const int*)d_in[2];
    const int*   col   = (const int*)d_in[3];
    const float* emb_w = (const float*)d_in[4];
    const float* emb_b = (const float*)d_in[5];
    const float* out_w = (const float*)d_in[6];
    const float* out_b = (const float*)d_in[7];
    const float* e_w1  = (const float*)d_in[8];
    const float* e_b1  = (const float*)d_in[9];
    const float* e_w2  = (const float*)d_in[10];
    const float* e_b2  = (const float*)d_in[11];
    const float* n_w1  = (const float*)d_in[12];
    const float* n_b1  = (const float*)d_in[13];
    const float* n_w2  = (const float*)d_in[14];
    const float* n_b2  = (const float*)d_in[15];
    const float* q_w1  = (const float*)d_in[16];
    const float* q_b1  = (const float*)d_in[17];
    const float* q_w2  = (const float*)d_in[18];
    const float* q_b2  = (const float*)d_in[19];
    const float* q_w3  = (const float*)d_in[20];

    size_t need = 49152 + ((size_t)NN*64*4 + (size_t)NE*2 + (size_t)NN*3
                   + (size_t)NE*2 + (size_t)NN*2 + 64) * sizeof(float);
    if (ws_size < need) return;

    u16*   w2f   = (u16*)d_ws;                       // 6*4096 bf16 frags (48 KB)
    float* fb    = (float*)((char*)d_ws + 49152);
    float* h64   = fb;                               // N*64 f32
    u32*   Pb    = (u32*)(h64 + (size_t)NN*64);      // N*32 u32 (bf16x2)
    u32*   Qb    = Pb + (size_t)NN*32;               // N*32 u32
    float* agg   = (float*)(Qb + (size_t)NN*32);     // N*64 f32
    float* d0S   = agg   + (size_t)NN*64;            // E (sorted)
    float* radS  = d0S   + (size_t)NE;               // E (sorted)
    float* xA    = radS  + (size_t)NE;               // N*3
    int*   rowS  = (int*)(xA + (size_t)NN*3);        // E
    int*   colS  = rowS  + (size_t)NE;               // E
    int*   deg   = colS  + (size_t)NE;               // N
    int*   base  = deg   + (size_t)NN;               // N

    float* out_h = (float*)d_out;
    float* out_x = out_h + (size_t)NN*16;

    dim3 th(256);
    dim3 nb((NN + 255)/256);
    dim3 eb(NE/256);
    dim3 t64b((NN + 63)/64);    // 64-node tiles for k_pq / k_node

    hipMemsetAsync(deg, 0, (size_t)NN*sizeof(int), stream);
    k_hist<<<eb, th, 0, stream>>>(row, deg);
    k_scan<<<1, th, 0, stream>>>(deg, base);
    k_scatter<<<eb, th, 0, stream>>>(row, col, base, rowS, colS);
    k_wconv<<<96, th, 0, stream>>>(e_w2, q_w2, w2f);

    k_radial<<<eb, th, 0, stream>>>(x_in, rowS, colS, d0S);
    k_embed<<<nb, th, 0, stream>>>(h_in, emb_w, emb_b, h64);

    for (int b = 0; b < 2; ++b) {
        const float* x_old;
        float*       x_new;
        const float* radp;
        if (b == 0) {
            x_old = x_in;  x_new = xA;    radp = d0S;
        } else {
            x_old = xA;    x_new = out_x; radp = radS;
            k_radial<<<eb, th, 0, stream>>>(x_old, rowS, colS, radS);
        }
        for (int i = 0; i < 2; ++i) {
            int l = b*2 + i;
            k_pq<<<t64b, th, 0, stream>>>(h64, e_w1 + (size_t)l*130*64,
                                          e_b1 + (size_t)l*64, Pb, Qb);
            hipMemsetAsync(agg, 0, (size_t)NN*64*sizeof(float), stream);
            k_edge<<<eb, th, 0, stream>>>(Pb, Qb, radp, d0S, rowS, colS,
                    e_w1 + (size_t)l*130*64 + 128*64,
                    w2f + (size_t)l*4096,
                    e_b2 + (size_t)l*64, agg);
            k_node<<<t64b, th, 0, stream>>>(h64, agg,
                    n_w1 + (size_t)l*128*64, n_b1 + (size_t)l*64,
                    n_w2 + (size_t)l*64*64, n_b2 + (size_t)l*64);
        }
        k_pq<<<t64b, th, 0, stream>>>(h64, q_w1 + (size_t)b*130*64,
                                      q_b1 + (size_t)b*64, Pb, Qb);
        hipMemcpyAsync(x_new, x_old, (size_t)NN*3*sizeof(float),
                       hipMemcpyDeviceToDevice, stream);
        k_coord<<<eb, th, 0, stream>>>(Pb, Qb, radp, d0S, rowS, colS,
                q_w1 + (size_t)b*130*64 + 128*64,
                w2f + (size_t)(4 + b)*4096,
                q_b2 + (size_t)b*64, q_w3 + (size_t)b*64, x_old, x_new);
    }
    k_out<<<nb, th, 0, stream>>>(h64, out_w, out_b, out_h);
}

// Round 6
// 1753.871 us; speedup vs baseline: 1.2062x; 1.2062x over previous
//
#include <hip/hip_runtime.h>

#define NN 50000
#define NE 800000

typedef unsigned int  u32;
typedef unsigned short u16;
typedef __attribute__((ext_vector_type(8))) short short8;
typedef __attribute__((ext_vector_type(4))) float f32x4;

union ABfrag { uint2 u2[2]; uint4 u4; short8 s8; };

__device__ __forceinline__ float silu_f(float v) {
    return v * (1.0f / (1.0f + __expf(-v)));
}
__device__ __forceinline__ u32 bfr(float x) {   // f32 -> bf16 (RNE), low 16 bits
    u32 u = __float_as_uint(x);
    u += 0x7fffu + ((u >> 16) & 1u);
    return u >> 16;
}
__device__ __forceinline__ float bff(u32 h) { return __uint_as_float(h << 16); }

// ---------------- embedding: h64 = h @ emb_w + emb_b  (N x 16 -> N x 64)
__global__ __launch_bounds__(256, 4) void k_embed(const float* __restrict__ h,
        const float* __restrict__ w, const float* __restrict__ b,
        float* __restrict__ h64) {
    int n = blockIdx.x * 256 + threadIdx.x;
    if (n >= NN) return;
    const float4* h4 = (const float4*)(h + (long)n * 16);
    float in[16];
    #pragma unroll
    for (int c = 0; c < 4; ++c) {
        float4 v = h4[c];
        in[4*c+0] = v.x; in[4*c+1] = v.y; in[4*c+2] = v.z; in[4*c+3] = v.w;
    }
    float acc[64];
    #pragma unroll
    for (int j = 0; j < 64; ++j) acc[j] = b[j];
    #pragma unroll
    for (int k = 0; k < 16; ++k) {
        #pragma unroll
        for (int j = 0; j < 64; ++j) acc[j] = fmaf(in[k], w[k*64 + j], acc[j]);
    }
    float4* o4 = (float4*)(h64 + (long)n * 64);
    #pragma unroll
    for (int c = 0; c < 16; ++c)
        o4[c] = make_float4(acc[4*c+0], acc[4*c+1], acc[4*c+2], acc[4*c+3]);
}

// ---------------- CSR-order build: histogram / scan / scatter ----------------
__global__ __launch_bounds__(256, 4) void k_hist(const int* __restrict__ row,
        int* __restrict__ deg) {
    int e = blockIdx.x * 256 + threadIdx.x;
    if (e < NE) atomicAdd(&deg[row[e]], 1);
}

__global__ __launch_bounds__(256) void k_scan(const int* __restrict__ deg,
        int* __restrict__ base) {
    __shared__ int s[256];
    const int CH = (NN + 255) / 256;
    int t = threadIdx.x;
    int lo = t * CH, hi = min(lo + CH, NN);
    int sum = 0;
    for (int i = lo; i < hi; ++i) sum += deg[i];
    s[t] = sum;
    __syncthreads();
    #pragma unroll
    for (int d = 1; d < 256; d <<= 1) {
        int v = (t >= d) ? s[t - d] : 0;
        __syncthreads();
        s[t] += v;
        __syncthreads();
    }
    int run = s[t] - sum;
    for (int i = lo; i < hi; ++i) { base[i] = run; run += deg[i]; }
}

__global__ __launch_bounds__(256, 4) void k_scatter(const int* __restrict__ row,
        const int* __restrict__ col, int* __restrict__ base,
        int* __restrict__ rowS, int* __restrict__ colS) {
    int e = blockIdx.x * 256 + threadIdx.x;
    if (e >= NE) return;
    int r = row[e];
    int p = atomicAdd(&base[r], 1);
    rowS[p] = r;
    colS[p] = col[e];
}

// ---------------- per-edge squared distance (sorted edge space)
__global__ __launch_bounds__(256, 4) void k_radial(const float* __restrict__ x,
        const int* __restrict__ rowS, const int* __restrict__ colS,
        float* __restrict__ radial) {
    int e = blockIdx.x * 256 + threadIdx.x;
    if (e >= NE) return;
    int r = rowS[e], c = colS[e];
    float dx = x[r*3+0] - x[c*3+0];
    float dy = x[r*3+1] - x[c*3+1];
    float dz = x[r*3+2] - x[c*3+2];
    radial[e] = dx*dx + dy*dy + dz*dz;
}

// ---------------- weight -> bf16 B-fragment tables
// [0, 24576): e_w2(4) + q_w2(2), 64x64 each, n in 0..3, s in 0..1
// [24576, 57344): n_w1(4), 128x64, n in 0..3, s in 0..3
// [57344, 73728): n_w2(4), 64x64
__global__ __launch_bounds__(256, 4) void k_wconv(const float* __restrict__ e_w2,
        const float* __restrict__ q_w2, const float* __restrict__ n_w1,
        const float* __restrict__ n_w2, u16* __restrict__ wf) {
    int t = blockIdx.x * 256 + threadIdx.x;
    if (t >= 73728) return;
    int j, lane, n, s, k, col;
    if (t < 24576) {
        int L = t >> 12, v = t & 4095;
        j = v & 7; lane = (v >> 3) & 63; int ns = v >> 9; n = ns >> 1; s = ns & 1;
        k = 8*(lane >> 4) + j + 32*s;
        col = 16*n + (lane & 15);
        const float* src = (L < 4) ? e_w2 + (size_t)L*4096 : q_w2 + (size_t)(L-4)*4096;
        wf[t] = (u16)bfr(src[k*64 + col]);
    } else if (t < 57344) {
        int u = t - 24576; int L = u >> 13, v = u & 8191;
        j = v & 7; lane = (v >> 3) & 63; int ns = v >> 9; n = ns >> 2; s = ns & 3;
        k = 8*(lane >> 4) + j + 32*s;
        col = 16*n + (lane & 15);
        wf[t] = (u16)bfr(n_w1[(size_t)L*8192 + k*64 + col]);
    } else {
        int u = t - 57344; int L = u >> 12, v = u & 4095;
        j = v & 7; lane = (v >> 3) & 63; int ns = v >> 9; n = ns >> 1; s = ns & 1;
        k = 8*(lane >> 4) + j + 32*s;
        col = 16*n + (lane & 15);
        wf[t] = (u16)bfr(n_w2[(size_t)L*4096 + k*64 + col]);
    }
}

// ---------------- P/Q: wave-uniform output quarter; coalesced store via LDS
__global__ __launch_bounds__(256, 4) void k_pq(const float* __restrict__ h64,
        const float* __restrict__ w1, const float* __restrict__ b1,
        u32* __restrict__ Pb, u32* __restrict__ Qb) {
    __shared__ u32 XP[64*34], XQ[64*34];
    int t = threadIdx.x, w = t >> 6, lane = t & 63;
    int n0 = blockIdx.x * 64;
    int n = min(n0 + lane, NN - 1);
    const float4* in4 = (const float4*)(h64 + (size_t)n * 64);
    float accP[16], accQ[16];
    #pragma unroll
    for (int j = 0; j < 16; ++j) { accP[j] = b1[16*w + j]; accQ[j] = 0.0f; }
    const float* w1b = w1 + 64 * 64;
    #pragma unroll
    for (int c = 0; c < 16; ++c) {
        float4 f = in4[c];
        float vv[4] = {f.x, f.y, f.z, f.w};
        #pragma unroll
        for (int u = 0; u < 4; ++u) {
            int k = 4*c + u;
            #pragma unroll
            for (int j = 0; j < 16; ++j) {
                accP[j] = fmaf(vv[u], w1 [k*64 + 16*w + j], accP[j]);
                accQ[j] = fmaf(vv[u], w1b[k*64 + 16*w + j], accQ[j]);
            }
        }
    }
    #pragma unroll
    for (int j = 0; j < 4; ++j) {
        uint2 p = make_uint2(bfr(accP[4*j+0]) | (bfr(accP[4*j+1]) << 16),
                             bfr(accP[4*j+2]) | (bfr(accP[4*j+3]) << 16));
        uint2 q = make_uint2(bfr(accQ[4*j+0]) | (bfr(accQ[4*j+1]) << 16),
                             bfr(accQ[4*j+2]) | (bfr(accQ[4*j+3]) << 16));
        *(uint2*)&XP[lane*34 + 8*w + 2*j] = p;
        *(uint2*)&XQ[lane*34 + 8*w + 2*j] = q;
    }
    __syncthreads();
    int node = t >> 2, part = t & 3;
    if (n0 + node < NN) {
        u32 b[8];
        #pragma unroll
        for (int j = 0; j < 8; ++j) b[j] = XP[node*34 + part*8 + j];
        uint4* dp = (uint4*)(Pb + (size_t)(n0 + node)*32 + part*8);
        dp[0] = make_uint4(b[0], b[1], b[2], b[3]);
        dp[1] = make_uint4(b[4], b[5], b[6], b[7]);
        #pragma unroll
        for (int j = 0; j < 8; ++j) b[j] = XQ[node*34 + part*8 + j];
        uint4* dq = (uint4*)(Qb + (size_t)(n0 + node)*32 + part*8);
        dq[0] = make_uint4(b[0], b[1], b[2], b[3]);
        dq[1] = make_uint4(b[4], b[5], b[6], b[7]);
    }
}

// ---------------- edge MLP: layer1 per-thread (bf16 P/Q), layer2 MFMA
__global__ __launch_bounds__(256, 4) void k_edge(
        const u32* __restrict__ Pb, const u32* __restrict__ Qb,
        const float* __restrict__ radial, const float* __restrict__ dist0,
        const int* __restrict__ rowS, const int* __restrict__ colS,
        const float* __restrict__ w1t,   // rows 128,129 of w1: [2][64]
        const u16* __restrict__ w2f,
        const float* __restrict__ b2,
        float* __restrict__ agg) {
    __shared__ u16 S_lds[4][4224];   // union: A [64][64] / M [64f][66e] bf16
    int tid = threadIdx.x;
    int w = tid >> 6, lane = tid & 63;
    int e = blockIdx.x * 256 + w * 64 + lane;   // NE % 256 == 0
    u16* Aw = S_lds[w];
    int r = rowS[e], c = colS[e];
    float rad = radial[e], d0 = dist0[e];
    const uint2* Pr = (const uint2*)(Pb + (size_t)r * 32);
    const uint2* Qc = (const uint2*)(Qb + (size_t)c * 32);
    int swz = (lane & 15) << 3;
    #pragma unroll
    for (int kc = 0; kc < 16; ++kc) {
        uint2 pu = Pr[kc], qu = Qc[kc];
        float p0 = bff(pu.x & 0xffffu), p1 = bff(pu.x >> 16);
        float p2 = bff(pu.y & 0xffffu), p3 = bff(pu.y >> 16);
        float q0 = bff(qu.x & 0xffffu), q1 = bff(qu.x >> 16);
        float q2 = bff(qu.y & 0xffffu), q3 = bff(qu.y >> 16);
        float h0 = silu_f(p0 + q0 + rad*w1t[4*kc+0] + d0*w1t[64+4*kc+0]);
        float h1 = silu_f(p1 + q1 + rad*w1t[4*kc+1] + d0*w1t[64+4*kc+1]);
        float h2 = silu_f(p2 + q2 + rad*w1t[4*kc+2] + d0*w1t[64+4*kc+2]);
        float h3 = silu_f(p3 + q3 + rad*w1t[4*kc+3] + d0*w1t[64+4*kc+3]);
        uint2 pk = make_uint2(bfr(h0) | (bfr(h1) << 16), bfr(h2) | (bfr(h3) << 16));
        *(uint2*)((char*)Aw + lane*128 + ((8*kc) ^ swz)) = pk;
    }
    __syncthreads();
    ABfrag bf[4][2];
    #pragma unroll
    for (int n = 0; n < 4; ++n)
        #pragma unroll
        for (int s = 0; s < 2; ++s)
            bf[n][s].u4 = *(const uint4*)(w2f + ((n*2 + s)*64 + lane)*8);
    int r0 = lane & 15, g = lane >> 4;
    f32x4 acc[4][4];
    #pragma unroll
    for (int t = 0; t < 4; ++t)
        #pragma unroll
        for (int n = 0; n < 4; ++n)
            acc[t][n] = (f32x4){0.f, 0.f, 0.f, 0.f};
    #pragma unroll
    for (int t = 0; t < 4; ++t) {
        #pragma unroll
        for (int s = 0; s < 2; ++s) {
            int boff = 16*g + 64*s;
            ABfrag af;
            af.u2[0] = *(uint2*)((char*)Aw + (16*t + r0)*128 + ( boff      ^ (r0 << 3)));
            af.u2[1] = *(uint2*)((char*)Aw + (16*t + r0)*128 + ((boff + 8) ^ (r0 << 3)));
            #pragma unroll
            for (int n = 0; n < 4; ++n)
                acc[t][n] = __builtin_amdgcn_mfma_f32_16x16x32_bf16(
                    af.s8, bf[n][s].s8, acc[t][n], 0, 0, 0);
        }
    }
    __syncthreads();   // all A reads complete before the M overlay writes
    u16* Mw = Aw;      // overlay: [64 feat][66 edge] bf16, row stride 132 B
    #pragma unroll
    for (int n = 0; n < 4; ++n) {
        float b2v = b2[16*n + r0];
        #pragma unroll
        for (int t = 0; t < 4; ++t) {
            f32x4 z = acc[t][n];
            u32 p0 = bfr(silu_f(z[0] + b2v)) | (bfr(silu_f(z[1] + b2v)) << 16);
            u32 p1 = bfr(silu_f(z[2] + b2v)) | (bfr(silu_f(z[3] + b2v)) << 16);
            *(uint2*)((char*)Mw + (16*n + r0)*132 + 32*t + 8*g) = make_uint2(p0, p1);
        }
    }
    __syncthreads();
    float racc = 0.0f;
    int cur = __builtin_amdgcn_readfirstlane(__shfl(r, 0));
    #pragma unroll
    for (int ch = 0; ch < 16; ++ch) {
        uint2 mm = *(uint2*)((char*)Mw + lane*132 + 8*ch);
        #pragma unroll
        for (int q = 0; q < 4; ++q) {
            int ee = 4*ch + q;
            u32 hu = ((q & 2) ? mm.y : mm.x) >> ((q & 1) * 16);
            float v = bff(hu & 0xffffu);
            int rr = __builtin_amdgcn_readfirstlane(__shfl(r, ee));
            if (rr != cur) {
                atomicAdd(&agg[(long)cur*64 + lane], racc);
                racc = 0.0f; cur = rr;
            }
            racc += v;
        }
    }
    atomicAdd(&agg[(long)cur*64 + lane], racc);
}

// ---------------- node MLP via MFMA: h += silu([h,agg/100]@w1+b1)@w2 + b2
__global__ __launch_bounds__(256, 4) void k_node(float* __restrict__ h64,
        const float* __restrict__ agg,
        const u16* __restrict__ w1f, const float* __restrict__ b1,
        const u16* __restrict__ w2f, const float* __restrict__ b2) {
    __shared__ u16 A0[64*64];   // k 0..63 (h), swizzled [64][128B]
    __shared__ u16 A1[64*64];   // k 64..127 (agg*0.01), swizzled
    __shared__ u16 H [64*64];   // hidden bf16, swizzled
    __shared__ u16 D [64*66];   // delta bf16 [node][66]
    int t = threadIdx.x, w = t >> 6, lane = t & 63;
    int nb0 = blockIdx.x * 64;
    #pragma unroll
    for (int i = 0; i < 8; ++i) {
        int idx = i*256 + t;
        int r = idx >> 5, c = idx & 31;
        int n = nb0 + r;
        float4 v = make_float4(0.f, 0.f, 0.f, 0.f);
        if (n < NN) {
            if (c < 16) v = ((const float4*)(h64 + (size_t)n*64))[c];
            else {
                float4 a = ((const float4*)(agg + (size_t)n*64))[c-16];
                v = make_float4(a.x*0.01f, a.y*0.01f, a.z*0.01f, a.w*0.01f);
            }
        }
        uint2 pk = make_uint2(bfr(v.x) | (bfr(v.y) << 16), bfr(v.z) | (bfr(v.w) << 16));
        u16* dst = (c < 16) ? A0 : A1;
        int cc = c & 15;
        *(uint2*)((char*)dst + r*128 + ((8*cc) ^ ((r & 15) << 3))) = pk;
    }
    __syncthreads();
    int r0 = lane & 15, g = lane >> 4;
    // ---- layer 1: wave w owns cols 16w..16w+15, K = 128 (4 slices)
    ABfrag bf1[4];
    #pragma unroll
    for (int s = 0; s < 4; ++s)
        bf1[s].u4 = *(const uint4*)(w1f + ((size_t)(w*4 + s)*64 + lane)*8);
    f32x4 acc[4];
    #pragma unroll
    for (int t4 = 0; t4 < 4; ++t4) acc[t4] = (f32x4){0.f, 0.f, 0.f, 0.f};
    #pragma unroll
    for (int t4 = 0; t4 < 4; ++t4) {
        #pragma unroll
        for (int s = 0; s < 4; ++s) {
            const u16* Ah = (s < 2) ? A0 : A1;
            int boff = 16*g + 64*(s & 1);
            ABfrag af;
            af.u2[0] = *(uint2*)((char*)Ah + (16*t4 + r0)*128 + ( boff      ^ (r0 << 3)));
            af.u2[1] = *(uint2*)((char*)Ah + (16*t4 + r0)*128 + ((boff + 8) ^ (r0 << 3)));
            acc[t4] = __builtin_amdgcn_mfma_f32_16x16x32_bf16(
                af.s8, bf1[s].s8, acc[t4], 0, 0, 0);
        }
    }
    float b1v = b1[16*w + r0];
    #pragma unroll
    for (int t4 = 0; t4 < 4; ++t4)
        #pragma unroll
        for (int q = 0; q < 4; ++q) {
            int rw = 16*t4 + 4*g + q;     // output node row (C layout)
            u16 hv = (u16)bfr(silu_f(acc[t4][q] + b1v));
            *(u16*)((char*)H + rw*128 + ((2*(16*w + r0)) ^ ((rw & 15) << 3))) = hv;
        }
    __syncthreads();
    // ---- layer 2: K = 64 (2 slices)
    ABfrag bf2[2];
    #pragma unroll
    for (int s = 0; s < 2; ++s)
        bf2[s].u4 = *(const uint4*)(w2f + ((size_t)(w*2 + s)*64 + lane)*8);
    f32x4 acc2[4];
    #pragma unroll
    for (int t4 = 0; t4 < 4; ++t4) acc2[t4] = (f32x4){0.f, 0.f, 0.f, 0.f};
    #pragma unroll
    for (int t4 = 0; t4 < 4; ++t4) {
        #pragma unroll
        for (int s = 0; s < 2; ++s) {
            int boff = 16*g + 64*s;
            ABfrag af;
            af.u2[0] = *(uint2*)((char*)H + (16*t4 + r0)*128 + ( boff      ^ (r0 << 3)));
            af.u2[1] = *(uint2*)((char*)H + (16*t4 + r0)*128 + ((boff + 8) ^ (r0 << 3)));
            acc2[t4] = __builtin_amdgcn_mfma_f32_16x16x32_bf16(
                af.s8, bf2[s].s8, acc2[t4], 0, 0, 0);
        }
    }
    float b2v = b2[16*w + r0];
    #pragma unroll
    for (int t4 = 0; t4 < 4; ++t4)
        #pragma unroll
        for (int q = 0; q < 4; ++q) {
            int rw = 16*t4 + 4*g + q;
            D[rw*66 + 16*w + r0] = (u16)bfr(acc2[t4][q] + b2v);
        }
    __syncthreads();
    // ---- residual RMW, fully coalesced float4
    #pragma unroll
    for (int i = 0; i < 4; ++i) {
        int idx = i*256 + t;
        int rr = idx >> 4, cc = idx & 15;
        int n = nb0 + rr;
        if (n < NN) {
            float4 v = ((const float4*)(h64 + (size_t)n*64))[cc];
            v.x += bff(D[rr*66 + 4*cc + 0]);
            v.y += bff(D[rr*66 + 4*cc + 1]);
            v.z += bff(D[rr*66 + 4*cc + 2]);
            v.w += bff(D[rr*66 + 4*cc + 3]);
            ((float4*)(h64 + (size_t)n*64))[cc] = v;
        }
    }
}

// ---------------- coordinate update: layer2 via MFMA, phi via shfl butterfly
__global__ __launch_bounds__(256, 4) void k_coord(
        const u32* __restrict__ Pb, const u32* __restrict__ Qb,
        const float* __restrict__ radial, const float* __restrict__ dist0,
        const int* __restrict__ rowS, const int* __restrict__ colS,
        const float* __restrict__ w1t, const u16* __restrict__ w2f,
        const float* __restrict__ b2, const float* __restrict__ w3,
        const float* __restrict__ x_old, float* __restrict__ x_new) {
    __shared__ u16 A_lds[4][4096];
    int tid = threadIdx.x;
    int w = tid >> 6, lane = tid & 63;
    int e = blockIdx.x * 256 + w * 64 + lane;
    u16* Aw = A_lds[w];
    int r = rowS[e], c = colS[e];
    float rad = radial[e], d0 = dist0[e];
    const uint2* Pr = (const uint2*)(Pb + (size_t)r * 32);
    const uint2* Qc = (const uint2*)(Qb + (size_t)c * 32);
    int swz = (lane & 15) << 3;
    #pragma unroll
    for (int kc = 0; kc < 16; ++kc) {
        uint2 pu = Pr[kc], qu = Qc[kc];
        float p0 = bff(pu.x & 0xffffu), p1 = bff(pu.x >> 16);
        float p2 = bff(pu.y & 0xffffu), p3 = bff(pu.y >> 16);
        float q0 = bff(qu.x & 0xffffu), q1 = bff(qu.x >> 16);
        float q2 = bff(qu.y & 0xffffu), q3 = bff(qu.y >> 16);
        float h0 = silu_f(p0 + q0 + rad*w1t[4*kc+0] + d0*w1t[64+4*kc+0]);
        float h1 = silu_f(p1 + q1 + rad*w1t[4*kc+1] + d0*w1t[64+4*kc+1]);
        float h2 = silu_f(p2 + q2 + rad*w1t[4*kc+2] + d0*w1t[64+4*kc+2]);
        float h3 = silu_f(p3 + q3 + rad*w1t[4*kc+3] + d0*w1t[64+4*kc+3]);
        uint2 pk = make_uint2(bfr(h0) | (bfr(h1) << 16), bfr(h2) | (bfr(h3) << 16));
        *(uint2*)((char*)Aw + lane*128 + ((8*kc) ^ swz)) = pk;
    }
    __syncthreads();
    ABfrag bf[4][2];
    #pragma unroll
    for (int n = 0; n < 4; ++n)
        #pragma unroll
        for (int s = 0; s < 2; ++s)
            bf[n][s].u4 = *(const uint4*)(w2f + ((n*2 + s)*64 + lane)*8);
    int r0 = lane & 15, g = lane >> 4;
    f32x4 acc[4][4];
    #pragma unroll
    for (int t = 0; t < 4; ++t)
        #pragma unroll
        for (int n = 0; n < 4; ++n)
            acc[t][n] = (f32x4){0.f, 0.f, 0.f, 0.f};
    #pragma unroll
    for (int t = 0; t < 4; ++t) {
        #pragma unroll
        for (int s = 0; s < 2; ++s) {
            int boff = 16*g + 64*s;
            ABfrag af;
            af.u2[0] = *(uint2*)((char*)Aw + (16*t + r0)*128 + ( boff      ^ (r0 << 3)));
            af.u2[1] = *(uint2*)((char*)Aw + (16*t + r0)*128 + ((boff + 8) ^ (r0 << 3)));
            #pragma unroll
            for (int n = 0; n < 4; ++n)
                acc[t][n] = __builtin_amdgcn_mfma_f32_16x16x32_bf16(
                    af.s8, bf[n][s].s8, acc[t][n], 0, 0, 0);
        }
    }
    float w3v[4], b2v[4];
    #pragma unroll
    for (int n = 0; n < 4; ++n) { w3v[n] = w3[16*n + r0]; b2v[n] = b2[16*n + r0]; }
    float ph[16];
    #pragma unroll
    for (int t = 0; t < 4; ++t)
        #pragma unroll
        for (int q = 0; q < 4; ++q) {
            float s = 0.f;
            #pragma unroll
            for (int n = 0; n < 4; ++n)
                s = fmaf(silu_f(acc[t][n][q] + b2v[n]), w3v[n], s);
            ph[t*4 + q] = s;
        }
    #pragma unroll
    for (int d = 1; d < 16; d <<= 1)
        #pragma unroll
        for (int i = 0; i < 16; ++i) ph[i] += __shfl_xor(ph[i], d);
    __syncthreads();
    float* phl = (float*)Aw;
    if (r0 == 0) {
        #pragma unroll
        for (int t = 0; t < 4; ++t)
            #pragma unroll
            for (int q = 0; q < 4; ++q)
                phl[16*t + 4*g + q] = ph[t*4 + q];
    }
    __syncthreads();
    float phi = phl[lane] * 0.01f;
    float dx = x_old[r*3+0] - x_old[c*3+0];
    float dy = x_old[r*3+1] - x_old[c*3+1];
    float dz = x_old[r*3+2] - x_old[c*3+2];
    float inv = phi / (sqrtf(rad + 1e-8f) + 1.0f);
    float tx = dx * inv, ty = dy * inv, tz = dz * inv;
    int rprev = __shfl_up(r, 1);
    bool head = (lane == 0) || (rprev != r);
    unsigned long long hm = __ballot(head);
    int runid = __popcll(hm & ((2ull << lane) - 1ull));
    #pragma unroll
    for (int d = 1; d < 64; d <<= 1) {
        float ox = __shfl_up(tx, d);
        float oy = __shfl_up(ty, d);
        float oz = __shfl_up(tz, d);
        int orid = __shfl_up(runid, d);
        if (lane >= d && orid == runid) { tx += ox; ty += oy; tz += oz; }
    }
    int rid_next = __shfl_down(runid, 1);
    bool tail = (lane == 63) || (rid_next != runid);
    if (tail) {
        atomicAdd(&x_new[r*3+0], tx);
        atomicAdd(&x_new[r*3+1], ty);
        atomicAdd(&x_new[r*3+2], tz);
    }
}

// ---------------- output projection: out = h64 @ out_w + out_b
__global__ __launch_bounds__(256, 4) void k_out(const float* __restrict__ h64,
        const float* __restrict__ w, const float* __restrict__ b,
        float* __restrict__ out) {
    int n = blockIdx.x * 256 + threadIdx.x;
    if (n >= NN) return;
    float acc[16];
    #pragma unroll
    for (int j = 0; j < 16; ++j) acc[j] = b[j];
    const float4* h4 = (const float4*)(h64 + (long)n*64);
    #pragma unroll
    for (int c = 0; c < 16; ++c) {
        float4 v = h4[c];
        float vv[4] = {v.x, v.y, v.z, v.w};
        #pragma unroll
        for (int t = 0; t < 4; ++t) {
            #pragma unroll
            for (int j = 0; j < 16; ++j)
                acc[j] = fmaf(vv[t], w[(4*c+t)*16 + j], acc[j]);
        }
    }
    float4* o4 = (float4*)(out + (long)n*16);
    #pragma unroll
    for (int cq = 0; cq < 4; ++cq)
        o4[cq] = make_float4(acc[4*cq+0],acc[4*cq+1],acc[4*cq+2],acc[4*cq+3]);
}

extern "C" void kernel_launch(void* const* d_in, const int* in_sizes, int n_in,
                              void* d_out, int out_size, void* d_ws, size_t ws_size,
                              hipStream_t stream) {
    const float* h_in  = (const float*)d_in[0];
    const float* x_in  = (const float*)d_in[1];
    const int*   row   = (const int*)d_in[2];
    const int*   col   = (const int*)d_in[3];
    const float* emb_w = (const float*)d_in[4];
    const float* emb_b = (const float*)d_in[5];
    const float* out_w = (const float*)d_in[6];
    const float* out_b = (const float*)d_in[7];
    const float* e_w1  = (const float*)d_in[8];
    const float* e_b1  = (const float*)d_in[9];
    const float* e_w2  = (const float*)d_in[10];
    const float* e_b2  = (const float*)d_in[11];
    const float* n_w1  = (const float*)d_in[12];
    const float* n_b1  = (const float*)d_in[13];
    const float* n_w2  = (const float*)d_in[14];
    const float* n_b2  = (const float*)d_in[15];
    const float* q_w1  = (const float*)d_in[16];
    const float* q_b1  = (const float*)d_in[17];
    const float* q_w2  = (const float*)d_in[18];
    const float* q_b2  = (const float*)d_in[19];
    const float* q_w3  = (const float*)d_in[20];

    const size_t WF_BYTES = 73728 * sizeof(u16);   // 144 KB frag tables
    size_t need = WF_BYTES + ((size_t)NN*64*4 + (size_t)NE*2 + (size_t)NN*3
                   + (size_t)NE*2 + (size_t)NN*2 + 64) * sizeof(float);
    if (ws_size < need) return;

    u16*   wf    = (u16*)d_ws;
    float* fb    = (float*)((char*)d_ws + WF_BYTES);
    float* h64   = fb;                               // N*64 f32
    u32*   Pb    = (u32*)(h64 + (size_t)NN*64);      // N*32 u32 (bf16x2)
    u32*   Qb    = Pb + (size_t)NN*32;               // N*32 u32
    float* agg   = (float*)(Qb + (size_t)NN*32);     // N*64 f32
    float* d0S   = agg   + (size_t)NN*64;            // E (sorted)
    float* radS  = d0S   + (size_t)NE;               // E (sorted)
    float* xA    = radS  + (size_t)NE;               // N*3
    int*   rowS  = (int*)(xA + (size_t)NN*3);        // E
    int*   colS  = rowS  + (size_t)NE;               // E
    int*   deg   = colS  + (size_t)NE;               // N
    int*   base  = deg   + (size_t)NN;               // N

    float* out_h = (float*)d_out;
    float* out_x = out_h + (size_t)NN*16;

    dim3 th(256);
    dim3 nb((NN + 255)/256);
    dim3 eb(NE/256);
    dim3 t64b((NN + 63)/64);    // 64-node tiles for k_pq / k_node

    hipMemsetAsync(deg, 0, (size_t)NN*sizeof(int), stream);
    k_hist<<<eb, th, 0, stream>>>(row, deg);
    k_scan<<<1, th, 0, stream>>>(deg, base);
    k_scatter<<<eb, th, 0, stream>>>(row, col, base, rowS, colS);
    k_wconv<<<288, th, 0, stream>>>(e_w2, q_w2, n_w1, n_w2, wf);

    k_radial<<<eb, th, 0, stream>>>(x_in, rowS, colS, d0S);
    k_embed<<<nb, th, 0, stream>>>(h_in, emb_w, emb_b, h64);

    const u16* nw1f = wf + 24576;
    const u16* nw2f = wf + 57344;

    for (int b = 0; b < 2; ++b) {
        const float* x_old;
        float*       x_new;
        const float* radp;
        if (b == 0) {
            x_old = x_in;  x_new = xA;    radp = d0S;
        } else {
            x_old = xA;    x_new = out_x; radp = radS;
            k_radial<<<eb, th, 0, stream>>>(x_old, rowS, colS, radS);
        }
        for (int i = 0; i < 2; ++i) {
            int l = b*2 + i;
            k_pq<<<t64b, th, 0, stream>>>(h64, e_w1 + (size_t)l*130*64,
                                          e_b1 + (size_t)l*64, Pb, Qb);
            hipMemsetAsync(agg, 0, (size_t)NN*64*sizeof(float), stream);
            k_edge<<<eb, th, 0, stream>>>(Pb, Qb, radp, d0S, rowS, colS,
                    e_w1 + (size_t)l*130*64 + 128*64,
                    wf + (size_t)l*4096,
                    e_b2 + (size_t)l*64, agg);
            k_node<<<t64b, th, 0, stream>>>(h64, agg,
                    nw1f + (size_t)l*8192, n_b1 + (size_t)l*64,
                    nw2f + (size_t)l*4096, n_b2 + (size_t)l*64);
        }
        k_pq<<<t64b, th, 0, stream>>>(h64, q_w1 + (size_t)b*130*64,
                                      q_b1 + (size_t)b*64, Pb, Qb);
        hipMemcpyAsync(x_new, x_old, (size_t)NN*3*sizeof(float),
                       hipMemcpyDeviceToDevice, stream);
        k_coord<<<eb, th, 0, stream>>>(Pb, Qb, radp, d0S, rowS, colS,
                q_w1 + (size_t)b*130*64 + 128*64,
                wf + (size_t)(4 + b)*4096,
                q_b2 + (size_t)b*64, q_w3 + (size_t)b*64, x_old, x_new);
    }
    k_out<<<nb, th, 0, stream>>>(h64, out_w, out_b, out_h);
}

// Round 7
// 880.010 us; speedup vs baseline: 2.4041x; 1.9930x over previous
//
#include <hip/hip_runtime.h>

#define NN 50000
#define NE 800000

typedef unsigned int  u32;
typedef unsigned short u16;
typedef __attribute__((ext_vector_type(8))) short short8;
typedef __attribute__((ext_vector_type(4))) float f32x4;

union ABfrag { uint2 u2[2]; uint4 u4; short8 s8; };

__device__ __forceinline__ float silu_f(float v) {
    return v * (1.0f / (1.0f + __expf(-v)));
}
__device__ __forceinline__ u32 bfr(float x) {   // f32 -> bf16 (RNE), low 16 bits
    u32 u = __float_as_uint(x);
    u += 0x7fffu + ((u >> 16) & 1u);
    return u >> 16;
}
__device__ __forceinline__ float bff(u32 h) { return __uint_as_float(h << 16); }

// ---------------- embedding: h64 = h @ emb_w + emb_b  (N x 16 -> N x 64)
__global__ __launch_bounds__(256, 4) void k_embed(const float* __restrict__ h,
        const float* __restrict__ w, const float* __restrict__ b,
        float* __restrict__ h64) {
    int n = blockIdx.x * 256 + threadIdx.x;
    if (n >= NN) return;
    const float4* h4 = (const float4*)(h + (long)n * 16);
    float in[16];
    #pragma unroll
    for (int c = 0; c < 4; ++c) {
        float4 v = h4[c];
        in[4*c+0] = v.x; in[4*c+1] = v.y; in[4*c+2] = v.z; in[4*c+3] = v.w;
    }
    float acc[64];
    #pragma unroll
    for (int j = 0; j < 64; ++j) acc[j] = b[j];
    #pragma unroll
    for (int k = 0; k < 16; ++k) {
        #pragma unroll
        for (int j = 0; j < 64; ++j) acc[j] = fmaf(in[k], w[k*64 + j], acc[j]);
    }
    float4* o4 = (float4*)(h64 + (long)n * 64);
    #pragma unroll
    for (int c = 0; c < 16; ++c)
        o4[c] = make_float4(acc[4*c+0], acc[4*c+1], acc[4*c+2], acc[4*c+3]);
}

// ---------------- CSR-order build: histogram / scan / scatter ----------------
__global__ __launch_bounds__(256, 4) void k_hist(const int* __restrict__ row,
        int* __restrict__ deg) {
    int e = blockIdx.x * 256 + threadIdx.x;
    if (e < NE) atomicAdd(&deg[row[e]], 1);
}

__global__ __launch_bounds__(256) void k_scan(const int* __restrict__ deg,
        int* __restrict__ base) {
    __shared__ int s[256];
    const int CH = (NN + 255) / 256;
    int t = threadIdx.x;
    int lo = t * CH, hi = min(lo + CH, NN);
    int sum = 0;
    for (int i = lo; i < hi; ++i) sum += deg[i];
    s[t] = sum;
    __syncthreads();
    #pragma unroll
    for (int d = 1; d < 256; d <<= 1) {
        int v = (t >= d) ? s[t - d] : 0;
        __syncthreads();
        s[t] += v;
        __syncthreads();
    }
    int run = s[t] - sum;
    for (int i = lo; i < hi; ++i) { base[i] = run; run += deg[i]; }
}

__global__ __launch_bounds__(256, 4) void k_scatter(const int* __restrict__ row,
        const int* __restrict__ col, int* __restrict__ base,
        int* __restrict__ rowS, int* __restrict__ colS) {
    int e = blockIdx.x * 256 + threadIdx.x;
    if (e >= NE) return;
    int r = row[e];
    int p = atomicAdd(&base[r], 1);
    rowS[p] = r;
    colS[p] = col[e];
}

// ---------------- per-edge squared distance (sorted edge space)
__global__ __launch_bounds__(256, 4) void k_radial(const float* __restrict__ x,
        const int* __restrict__ rowS, const int* __restrict__ colS,
        float* __restrict__ radial) {
    int e = blockIdx.x * 256 + threadIdx.x;
    if (e >= NE) return;
    int r = rowS[e], c = colS[e];
    float dx = x[r*3+0] - x[c*3+0];
    float dy = x[r*3+1] - x[c*3+1];
    float dz = x[r*3+2] - x[c*3+2];
    radial[e] = dx*dx + dy*dy + dz*dz;
}

// ---------------- weight -> bf16 B-fragment tables
// [0, 24576):       e_w2(4) + q_w2(2), 64x64
// [24576, 57344):   n_w1(4), 128x64
// [57344, 73728):   n_w2(4), 64x64
// [73728, 122880):  P/Q halves of e_w1(4)+q_w1(2): per L, [P 4096 | Q 4096]
__global__ __launch_bounds__(256, 4) void k_wconv(const float* __restrict__ e_w2,
        const float* __restrict__ q_w2, const float* __restrict__ n_w1,
        const float* __restrict__ n_w2, const float* __restrict__ e_w1,
        const float* __restrict__ q_w1, u16* __restrict__ wf) {
    int t = blockIdx.x * 256 + threadIdx.x;
    if (t >= 122880) return;
    int j, lane, n, s, k, col;
    if (t < 24576) {
        int L = t >> 12, v = t & 4095;
        j = v & 7; lane = (v >> 3) & 63; int ns = v >> 9; n = ns >> 1; s = ns & 1;
        k = 8*(lane >> 4) + j + 32*s;
        col = 16*n + (lane & 15);
        const float* src = (L < 4) ? e_w2 + (size_t)L*4096 : q_w2 + (size_t)(L-4)*4096;
        wf[t] = (u16)bfr(src[k*64 + col]);
    } else if (t < 57344) {
        int u = t - 24576; int L = u >> 13, v = u & 8191;
        j = v & 7; lane = (v >> 3) & 63; int ns = v >> 9; n = ns >> 2; s = ns & 3;
        k = 8*(lane >> 4) + j + 32*s;
        col = 16*n + (lane & 15);
        wf[t] = (u16)bfr(n_w1[(size_t)L*8192 + k*64 + col]);
    } else if (t < 73728) {
        int u = t - 57344; int L = u >> 12, v = u & 4095;
        j = v & 7; lane = (v >> 3) & 63; int ns = v >> 9; n = ns >> 1; s = ns & 1;
        k = 8*(lane >> 4) + j + 32*s;
        col = 16*n + (lane & 15);
        wf[t] = (u16)bfr(n_w2[(size_t)L*4096 + k*64 + col]);
    } else {
        int u = t - 73728;
        int L = u >> 13;            // 0..5 (0..3 edge, 4..5 coord)
        int v = u & 8191;
        int m = v >> 12;            // 0 = P (rows 0..63), 1 = Q (rows 64..127)
        int v2 = v & 4095;
        j = v2 & 7; lane = (v2 >> 3) & 63; int ns = v2 >> 9; n = ns >> 1; s = ns & 1;
        k = 8*(lane >> 4) + j + 32*s;
        col = 16*n + (lane & 15);
        const float* src = (L < 4) ? e_w1 + (size_t)L*130*64
                                   : q_w1 + (size_t)(L-4)*130*64;
        wf[t] = (u16)bfr(src[(size_t)(m*64 + k)*64 + col]);
    }
}

// ---------------- P/Q via MFMA: P = h@W[0:64]+b1, Q = h@W[64:128]
__global__ __launch_bounds__(256, 4) void k_pq(const float* __restrict__ h64,
        const u16* __restrict__ wpf,   // [P frags 4096 | Q frags 4096]
        const float* __restrict__ b1,
        u32* __restrict__ Pb, u32* __restrict__ Qb) {
    __shared__ u16 A[64*64];           // swizzled bf16 [node][64]
    __shared__ u16 XP[64*70], XQ[64*70];   // [node][feat], stride 70 (2-way banks)
    int t = threadIdx.x, w = t >> 6, lane = t & 63;
    int nb0 = blockIdx.x * 64;
    #pragma unroll
    for (int i = 0; i < 4; ++i) {
        int idx = i*256 + t;
        int r = idx >> 4, c = idx & 15;
        int n = nb0 + r;
        float4 v = make_float4(0.f, 0.f, 0.f, 0.f);
        if (n < NN) v = ((const float4*)(h64 + (size_t)n*64))[c];
        uint2 pk = make_uint2(bfr(v.x) | (bfr(v.y) << 16), bfr(v.z) | (bfr(v.w) << 16));
        *(uint2*)((char*)A + r*128 + ((8*c) ^ ((r & 15) << 3))) = pk;
    }
    __syncthreads();
    int r0 = lane & 15, g = lane >> 4;
    ABfrag bp[2], bq[2];
    #pragma unroll
    for (int s = 0; s < 2; ++s) {
        bp[s].u4 = *(const uint4*)(wpf + ((size_t)(w*2 + s)*64 + lane)*8);
        bq[s].u4 = *(const uint4*)(wpf + 4096 + ((size_t)(w*2 + s)*64 + lane)*8);
    }
    f32x4 aP[4], aQ[4];
    #pragma unroll
    for (int t4 = 0; t4 < 4; ++t4) {
        aP[t4] = (f32x4){0.f, 0.f, 0.f, 0.f};
        aQ[t4] = (f32x4){0.f, 0.f, 0.f, 0.f};
    }
    #pragma unroll
    for (int t4 = 0; t4 < 4; ++t4) {
        #pragma unroll
        for (int s = 0; s < 2; ++s) {
            int boff = 16*g + 64*s;
            ABfrag af;
            af.u2[0] = *(uint2*)((char*)A + (16*t4 + r0)*128 + ( boff      ^ (r0 << 3)));
            af.u2[1] = *(uint2*)((char*)A + (16*t4 + r0)*128 + ((boff + 8) ^ (r0 << 3)));
            aP[t4] = __builtin_amdgcn_mfma_f32_16x16x32_bf16(af.s8, bp[s].s8, aP[t4], 0, 0, 0);
            aQ[t4] = __builtin_amdgcn_mfma_f32_16x16x32_bf16(af.s8, bq[s].s8, aQ[t4], 0, 0, 0);
        }
    }
    float bv = b1[16*w + r0];
    #pragma unroll
    for (int t4 = 0; t4 < 4; ++t4)
        #pragma unroll
        for (int q = 0; q < 4; ++q) {
            int rw = 16*t4 + 4*g + q;       // node row (C layout)
            XP[rw*70 + 16*w + r0] = (u16)bfr(aP[t4][q] + bv);
            XQ[rw*70 + 16*w + r0] = (u16)bfr(aQ[t4][q]);
        }
    __syncthreads();
    int node = t >> 2, part = t & 3;
    if (nb0 + node < NN) {
        const u32* XPw = (const u32*)XP;
        const u32* XQw = (const u32*)XQ;
        u32 b[8];
        #pragma unroll
        for (int j = 0; j < 8; ++j) b[j] = XPw[node*35 + 8*part + j];
        uint4* dp = (uint4*)(Pb + (size_t)(nb0 + node)*32 + part*8);
        dp[0] = make_uint4(b[0], b[1], b[2], b[3]);
        dp[1] = make_uint4(b[4], b[5], b[6], b[7]);
        #pragma unroll
        for (int j = 0; j < 8; ++j) b[j] = XQw[node*35 + 8*part + j];
        uint4* dq = (uint4*)(Qb + (size_t)(nb0 + node)*32 + part*8);
        dq[0] = make_uint4(b[0], b[1], b[2], b[3]);
        dq[1] = make_uint4(b[4], b[5], b[6], b[7]);
    }
}

// ---------------- edge MLP: layer1 per-thread (bf16 P/Q), layer2 MFMA
__global__ __launch_bounds__(256, 4) void k_edge(
        const u32* __restrict__ Pb, const u32* __restrict__ Qb,
        const float* __restrict__ radial, const float* __restrict__ dist0,
        const int* __restrict__ rowS, const int* __restrict__ colS,
        const float* __restrict__ w1t,   // rows 128,129 of w1: [2][64]
        const u16* __restrict__ w2f,
        const float* __restrict__ b2,
        float* __restrict__ agg) {
    __shared__ u16 S_lds[4][4224];   // union: A [64][64] / M [64f][66e] bf16
    int tid = threadIdx.x;
    int w = tid >> 6, lane = tid & 63;
    int e = blockIdx.x * 256 + w * 64 + lane;   // NE % 256 == 0
    u16* Aw = S_lds[w];
    int r = rowS[e], c = colS[e];
    float rad = radial[e], d0 = dist0[e];
    const uint2* Pr = (const uint2*)(Pb + (size_t)r * 32);
    const uint2* Qc = (const uint2*)(Qb + (size_t)c * 32);
    int swz = (lane & 15) << 3;
    #pragma unroll
    for (int kc = 0; kc < 16; ++kc) {
        uint2 pu = Pr[kc], qu = Qc[kc];
        float p0 = bff(pu.x & 0xffffu), p1 = bff(pu.x >> 16);
        float p2 = bff(pu.y & 0xffffu), p3 = bff(pu.y >> 16);
        float q0 = bff(qu.x & 0xffffu), q1 = bff(qu.x >> 16);
        float q2 = bff(qu.y & 0xffffu), q3 = bff(qu.y >> 16);
        float h0 = silu_f(p0 + q0 + rad*w1t[4*kc+0] + d0*w1t[64+4*kc+0]);
        float h1 = silu_f(p1 + q1 + rad*w1t[4*kc+1] + d0*w1t[64+4*kc+1]);
        float h2 = silu_f(p2 + q2 + rad*w1t[4*kc+2] + d0*w1t[64+4*kc+2]);
        float h3 = silu_f(p3 + q3 + rad*w1t[4*kc+3] + d0*w1t[64+4*kc+3]);
        uint2 pk = make_uint2(bfr(h0) | (bfr(h1) << 16), bfr(h2) | (bfr(h3) << 16));
        *(uint2*)((char*)Aw + lane*128 + ((8*kc) ^ swz)) = pk;
    }
    __syncthreads();
    ABfrag bf[4][2];
    #pragma unroll
    for (int n = 0; n < 4; ++n)
        #pragma unroll
        for (int s = 0; s < 2; ++s)
            bf[n][s].u4 = *(const uint4*)(w2f + ((n*2 + s)*64 + lane)*8);
    int r0 = lane & 15, g = lane >> 4;
    f32x4 acc[4][4];
    #pragma unroll
    for (int t = 0; t < 4; ++t)
        #pragma unroll
        for (int n = 0; n < 4; ++n)
            acc[t][n] = (f32x4){0.f, 0.f, 0.f, 0.f};
    #pragma unroll
    for (int t = 0; t < 4; ++t) {
        #pragma unroll
        for (int s = 0; s < 2; ++s) {
            int boff = 16*g + 64*s;
            ABfrag af;
            af.u2[0] = *(uint2*)((char*)Aw + (16*t + r0)*128 + ( boff      ^ (r0 << 3)));
            af.u2[1] = *(uint2*)((char*)Aw + (16*t + r0)*128 + ((boff + 8) ^ (r0 << 3)));
            #pragma unroll
            for (int n = 0; n < 4; ++n)
                acc[t][n] = __builtin_amdgcn_mfma_f32_16x16x32_bf16(
                    af.s8, bf[n][s].s8, acc[t][n], 0, 0, 0);
        }
    }
    __syncthreads();   // all A reads complete before the M overlay writes
    u16* Mw = Aw;      // overlay: [64 feat][66 edge] bf16, row stride 132 B
    #pragma unroll
    for (int n = 0; n < 4; ++n) {
        float b2v = b2[16*n + r0];
        #pragma unroll
        for (int t = 0; t < 4; ++t) {
            f32x4 z = acc[t][n];
            u32 p0 = bfr(silu_f(z[0] + b2v)) | (bfr(silu_f(z[1] + b2v)) << 16);
            u32 p1 = bfr(silu_f(z[2] + b2v)) | (bfr(silu_f(z[3] + b2v)) << 16);
            *(uint2*)((char*)Mw + (16*n + r0)*132 + 32*t + 8*g) = make_uint2(p0, p1);
        }
    }
    __syncthreads();
    float racc = 0.0f;
    int cur = __builtin_amdgcn_readfirstlane(__shfl(r, 0));
    #pragma unroll
    for (int ch = 0; ch < 16; ++ch) {
        uint2 mm = *(uint2*)((char*)Mw + lane*132 + 8*ch);
        #pragma unroll
        for (int q = 0; q < 4; ++q) {
            int ee = 4*ch + q;
            u32 hu = ((q & 2) ? mm.y : mm.x) >> ((q & 1) * 16);
            float v = bff(hu & 0xffffu);
            int rr = __builtin_amdgcn_readfirstlane(__shfl(r, ee));
            if (rr != cur) {
                atomicAdd(&agg[(long)cur*64 + lane], racc);
                racc = 0.0f; cur = rr;
            }
            racc += v;
        }
    }
    atomicAdd(&agg[(long)cur*64 + lane], racc);
}

// ---------------- node MLP via MFMA: h += silu([h,agg/100]@w1+b1)@w2 + b2
__global__ __launch_bounds__(256, 4) void k_node(float* __restrict__ h64,
        const float* __restrict__ agg,
        const u16* __restrict__ w1f, const float* __restrict__ b1,
        const u16* __restrict__ w2f, const float* __restrict__ b2) {
    __shared__ u16 A0[64*64];   // k 0..63 (h), swizzled [64][128B]
    __shared__ u16 A1[64*64];   // k 64..127 (agg*0.01), swizzled
    __shared__ u16 H [64*64];   // hidden bf16, swizzled
    __shared__ u16 D [64*66];   // delta bf16 [node][66]
    int t = threadIdx.x, w = t >> 6, lane = t & 63;
    int nb0 = blockIdx.x * 64;
    #pragma unroll
    for (int i = 0; i < 8; ++i) {
        int idx = i*256 + t;
        int r = idx >> 5, c = idx & 31;
        int n = nb0 + r;
        float4 v = make_float4(0.f, 0.f, 0.f, 0.f);
        if (n < NN) {
            if (c < 16) v = ((const float4*)(h64 + (size_t)n*64))[c];
            else {
                float4 a = ((const float4*)(agg + (size_t)n*64))[c-16];
                v = make_float4(a.x*0.01f, a.y*0.01f, a.z*0.01f, a.w*0.01f);
            }
        }
        uint2 pk = make_uint2(bfr(v.x) | (bfr(v.y) << 16), bfr(v.z) | (bfr(v.w) << 16));
        u16* dst = (c < 16) ? A0 : A1;
        int cc = c & 15;
        *(uint2*)((char*)dst + r*128 + ((8*cc) ^ ((r & 15) << 3))) = pk;
    }
    __syncthreads();
    int r0 = lane & 15, g = lane >> 4;
    ABfrag bf1[4];
    #pragma unroll
    for (int s = 0; s < 4; ++s)
        bf1[s].u4 = *(const uint4*)(w1f + ((size_t)(w*4 + s)*64 + lane)*8);
    f32x4 acc[4];
    #pragma unroll
    for (int t4 = 0; t4 < 4; ++t4) acc[t4] = (f32x4){0.f, 0.f, 0.f, 0.f};
    #pragma unroll
    for (int t4 = 0; t4 < 4; ++t4) {
        #pragma unroll
        for (int s = 0; s < 4; ++s) {
            const u16* Ah = (s < 2) ? A0 : A1;
            int boff = 16*g + 64*(s & 1);
            ABfrag af;
            af.u2[0] = *(uint2*)((char*)Ah + (16*t4 + r0)*128 + ( boff      ^ (r0 << 3)));
            af.u2[1] = *(uint2*)((char*)Ah + (16*t4 + r0)*128 + ((boff + 8) ^ (r0 << 3)));
            acc[t4] = __builtin_amdgcn_mfma_f32_16x16x32_bf16(
                af.s8, bf1[s].s8, acc[t4], 0, 0, 0);
        }
    }
    float b1v = b1[16*w + r0];
    #pragma unroll
    for (int t4 = 0; t4 < 4; ++t4)
        #pragma unroll
        for (int q = 0; q < 4; ++q) {
            int rw = 16*t4 + 4*g + q;
            u16 hv = (u16)bfr(silu_f(acc[t4][q] + b1v));
            *(u16*)((char*)H + rw*128 + ((2*(16*w + r0)) ^ ((rw & 15) << 3))) = hv;
        }
    __syncthreads();
    ABfrag bf2[2];
    #pragma unroll
    for (int s = 0; s < 2; ++s)
        bf2[s].u4 = *(const uint4*)(w2f + ((size_t)(w*2 + s)*64 + lane)*8);
    f32x4 acc2[4];
    #pragma unroll
    for (int t4 = 0; t4 < 4; ++t4) acc2[t4] = (f32x4){0.f, 0.f, 0.f, 0.f};
    #pragma unroll
    for (int t4 = 0; t4 < 4; ++t4) {
        #pragma unroll
        for (int s = 0; s < 2; ++s) {
            int boff = 16*g + 64*s;
            ABfrag af;
            af.u2[0] = *(uint2*)((char*)H + (16*t4 + r0)*128 + ( boff      ^ (r0 << 3)));
            af.u2[1] = *(uint2*)((char*)H + (16*t4 + r0)*128 + ((boff + 8) ^ (r0 << 3)));
            acc2[t4] = __builtin_amdgcn_mfma_f32_16x16x32_bf16(
                af.s8, bf2[s].s8, acc2[t4], 0, 0, 0);
        }
    }
    float b2v = b2[16*w + r0];
    #pragma unroll
    for (int t4 = 0; t4 < 4; ++t4)
        #pragma unroll
        for (int q = 0; q < 4; ++q) {
            int rw = 16*t4 + 4*g + q;
            D[rw*66 + 16*w + r0] = (u16)bfr(acc2[t4][q] + b2v);
        }
    __syncthreads();
    #pragma unroll
    for (int i = 0; i < 4; ++i) {
        int idx = i*256 + t;
        int rr = idx >> 4, cc = idx & 15;
        int n = nb0 + rr;
        if (n < NN) {
            float4 v = ((const float4*)(h64 + (size_t)n*64))[cc];
            v.x += bff(D[rr*66 + 4*cc + 0]);
            v.y += bff(D[rr*66 + 4*cc + 1]);
            v.z += bff(D[rr*66 + 4*cc + 2]);
            v.w += bff(D[rr*66 + 4*cc + 3]);
            ((float4*)(h64 + (size_t)n*64))[cc] = v;
        }
    }
}

// ---------------- coordinate update: layer2 via MFMA, phi via shfl butterfly
__global__ __launch_bounds__(256, 4) void k_coord(
        const u32* __restrict__ Pb, const u32* __restrict__ Qb,
        const float* __restrict__ radial, const float* __restrict__ dist0,
        const int* __restrict__ rowS, const int* __restrict__ colS,
        const float* __restrict__ w1t, const u16* __restrict__ w2f,
        const float* __restrict__ b2, const float* __restrict__ w3,
        const float* __restrict__ x_old, float* __restrict__ x_new) {
    __shared__ u16 A_lds[4][4096];
    int tid = threadIdx.x;
    int w = tid >> 6, lane = tid & 63;
    int e = blockIdx.x * 256 + w * 64 + lane;
    u16* Aw = A_lds[w];
    int r = rowS[e], c = colS[e];
    float rad = radial[e], d0 = dist0[e];
    const uint2* Pr = (const uint2*)(Pb + (size_t)r * 32);
    const uint2* Qc = (const uint2*)(Qb + (size_t)c * 32);
    int swz = (lane & 15) << 3;
    #pragma unroll
    for (int kc = 0; kc < 16; ++kc) {
        uint2 pu = Pr[kc], qu = Qc[kc];
        float p0 = bff(pu.x & 0xffffu), p1 = bff(pu.x >> 16);
        float p2 = bff(pu.y & 0xffffu), p3 = bff(pu.y >> 16);
        float q0 = bff(qu.x & 0xffffu), q1 = bff(qu.x >> 16);
        float q2 = bff(qu.y & 0xffffu), q3 = bff(qu.y >> 16);
        float h0 = silu_f(p0 + q0 + rad*w1t[4*kc+0] + d0*w1t[64+4*kc+0]);
        float h1 = silu_f(p1 + q1 + rad*w1t[4*kc+1] + d0*w1t[64+4*kc+1]);
        float h2 = silu_f(p2 + q2 + rad*w1t[4*kc+2] + d0*w1t[64+4*kc+2]);
        float h3 = silu_f(p3 + q3 + rad*w1t[4*kc+3] + d0*w1t[64+4*kc+3]);
        uint2 pk = make_uint2(bfr(h0) | (bfr(h1) << 16), bfr(h2) | (bfr(h3) << 16));
        *(uint2*)((char*)Aw + lane*128 + ((8*kc) ^ swz)) = pk;
    }
    __syncthreads();
    ABfrag bf[4][2];
    #pragma unroll
    for (int n = 0; n < 4; ++n)
        #pragma unroll
        for (int s = 0; s < 2; ++s)
            bf[n][s].u4 = *(const uint4*)(w2f + ((n*2 + s)*64 + lane)*8);
    int r0 = lane & 15, g = lane >> 4;
    f32x4 acc[4][4];
    #pragma unroll
    for (int t = 0; t < 4; ++t)
        #pragma unroll
        for (int n = 0; n < 4; ++n)
            acc[t][n] = (f32x4){0.f, 0.f, 0.f, 0.f};
    #pragma unroll
    for (int t = 0; t < 4; ++t) {
        #pragma unroll
        for (int s = 0; s < 2; ++s) {
            int boff = 16*g + 64*s;
            ABfrag af;
            af.u2[0] = *(uint2*)((char*)Aw + (16*t + r0)*128 + ( boff      ^ (r0 << 3)));
            af.u2[1] = *(uint2*)((char*)Aw + (16*t + r0)*128 + ((boff + 8) ^ (r0 << 3)));
            #pragma unroll
            for (int n = 0; n < 4; ++n)
                acc[t][n] = __builtin_amdgcn_mfma_f32_16x16x32_bf16(
                    af.s8, bf[n][s].s8, acc[t][n], 0, 0, 0);
        }
    }
    float w3v[4], b2v[4];
    #pragma unroll
    for (int n = 0; n < 4; ++n) { w3v[n] = w3[16*n + r0]; b2v[n] = b2[16*n + r0]; }
    float ph[16];
    #pragma unroll
    for (int t = 0; t < 4; ++t)
        #pragma unroll
        for (int q = 0; q < 4; ++q) {
            float s = 0.f;
            #pragma unroll
            for (int n = 0; n < 4; ++n)
                s = fmaf(silu_f(acc[t][n][q] + b2v[n]), w3v[n], s);
            ph[t*4 + q] = s;
        }
    #pragma unroll
    for (int d = 1; d < 16; d <<= 1)
        #pragma unroll
        for (int i = 0; i < 16; ++i) ph[i] += __shfl_xor(ph[i], d);
    __syncthreads();
    float* phl = (float*)Aw;
    if (r0 == 0) {
        #pragma unroll
        for (int t = 0; t < 4; ++t)
            #pragma unroll
            for (int q = 0; q < 4; ++q)
                phl[16*t + 4*g + q] = ph[t*4 + q];
    }
    __syncthreads();
    float phi = phl[lane] * 0.01f;
    float dx = x_old[r*3+0] - x_old[c*3+0];
    float dy = x_old[r*3+1] - x_old[c*3+1];
    float dz = x_old[r*3+2] - x_old[c*3+2];
    float inv = phi / (sqrtf(rad + 1e-8f) + 1.0f);
    float tx = dx * inv, ty = dy * inv, tz = dz * inv;
    int rprev = __shfl_up(r, 1);
    bool head = (lane == 0) || (rprev != r);
    unsigned long long hm = __ballot(head);
    int runid = __popcll(hm & ((2ull << lane) - 1ull));
    #pragma unroll
    for (int d = 1; d < 64; d <<= 1) {
        float ox = __shfl_up(tx, d);
        float oy = __shfl_up(ty, d);
        float oz = __shfl_up(tz, d);
        int orid = __shfl_up(runid, d);
        if (lane >= d && orid == runid) { tx += ox; ty += oy; tz += oz; }
    }
    int rid_next = __shfl_down(runid, 1);
    bool tail = (lane == 63) || (rid_next != runid);
    if (tail) {
        atomicAdd(&x_new[r*3+0], tx);
        atomicAdd(&x_new[r*3+1], ty);
        atomicAdd(&x_new[r*3+2], tz);
    }
}

// ---------------- output projection: out = h64 @ out_w + out_b
__global__ __launch_bounds__(256, 4) void k_out(const float* __restrict__ h64,
        const float* __restrict__ w, const float* __restrict__ b,
        float* __restrict__ out) {
    int n = blockIdx.x * 256 + threadIdx.x;
    if (n >= NN) return;
    float acc[16];
    #pragma unroll
    for (int j = 0; j < 16; ++j) acc[j] = b[j];
    const float4* h4 = (const float4*)(h64 + (long)n*64);
    #pragma unroll
    for (int c = 0; c < 16; ++c) {
        float4 v = h4[c];
        float vv[4] = {v.x, v.y, v.z, v.w};
        #pragma unroll
        for (int t = 0; t < 4; ++t) {
            #pragma unroll
            for (int j = 0; j < 16; ++j)
                acc[j] = fmaf(vv[t], w[(4*c+t)*16 + j], acc[j]);
        }
    }
    float4* o4 = (float4*)(out + (long)n*16);
    #pragma unroll
    for (int cq = 0; cq < 4; ++cq)
        o4[cq] = make_float4(acc[4*cq+0],acc[4*cq+1],acc[4*cq+2],acc[4*cq+3]);
}

extern "C" void kernel_launch(void* const* d_in, const int* in_sizes, int n_in,
                              void* d_out, int out_size, void* d_ws, size_t ws_size,
                              hipStream_t stream) {
    const float* h_in  = (const float*)d_in[0];
    const float* x_in  = (const float*)d_in[1];
    const int*   row   = (const int*)d_in[2];
    const int*   col   = (const int*)d_in[3];
    const float* emb_w = (const float*)d_in[4];
    const float* emb_b = (const float*)d_in[5];
    const float* out_w = (const float*)d_in[6];
    const float* out_b = (const float*)d_in[7];
    const float* e_w1  = (const float*)d_in[8];
    const float* e_b1  = (const float*)d_in[9];
    const float* e_w2  = (const float*)d_in[10];
    const float* e_b2  = (const float*)d_in[11];
    const float* n_w1  = (const float*)d_in[12];
    const float* n_b1  = (const float*)d_in[13];
    const float* n_w2  = (const float*)d_in[14];
    const float* n_b2  = (const float*)d_in[15];
    const float* q_w1  = (const float*)d_in[16];
    const float* q_b1  = (const float*)d_in[17];
    const float* q_w2  = (const float*)d_in[18];
    const float* q_b2  = (const float*)d_in[19];
    const float* q_w3  = (const float*)d_in[20];

    const size_t WF_N = 122880;                      // frag entries
    const size_t WF_BYTES = WF_N * sizeof(u16);      // 240 KB
    size_t need = WF_BYTES + ((size_t)NN*64*4 + (size_t)NE*2 + (size_t)NN*3
                   + (size_t)NE*2 + (size_t)NN*2 + 64) * sizeof(float);
    if (ws_size < need) return;

    u16*   wf    = (u16*)d_ws;
    float* fb    = (float*)((char*)d_ws + WF_BYTES);
    float* h64   = fb;                               // N*64 f32
    u32*   Pb    = (u32*)(h64 + (size_t)NN*64);      // N*32 u32 (bf16x2)
    u32*   Qb    = Pb + (size_t)NN*32;               // N*32 u32
    float* agg   = (float*)(Qb + (size_t)NN*32);     // N*64 f32
    float* d0S   = agg   + (size_t)NN*64;            // E (sorted)
    float* radS  = d0S   + (size_t)NE;               // E (sorted)
    float* xA    = radS  + (size_t)NE;               // N*3
    int*   rowS  = (int*)(xA + (size_t)NN*3);        // E
    int*   colS  = rowS  + (size_t)NE;               // E
    int*   deg   = colS  + (size_t)NE;               // N
    int*   base  = deg   + (size_t)NN;               // N

    float* out_h = (float*)d_out;
    float* out_x = out_h + (size_t)NN*16;

    dim3 th(256);
    dim3 nb((NN + 255)/256);
    dim3 eb(NE/256);
    dim3 t64b((NN + 63)/64);    // 64-node tiles for k_pq / k_node

    hipMemsetAsync(deg, 0, (size_t)NN*sizeof(int), stream);
    k_hist<<<eb, th, 0, stream>>>(row, deg);
    k_scan<<<1, th, 0, stream>>>(deg, base);
    k_scatter<<<eb, th, 0, stream>>>(row, col, base, rowS, colS);
    k_wconv<<<480, th, 0, stream>>>(e_w2, q_w2, n_w1, n_w2, e_w1, q_w1, wf);

    k_radial<<<eb, th, 0, stream>>>(x_in, rowS, colS, d0S);
    k_embed<<<nb, th, 0, stream>>>(h_in, emb_w, emb_b, h64);

    const u16* nw1f = wf + 24576;
    const u16* nw2f = wf + 57344;
    const u16* pqf  = wf + 73728;   // + L*8192, L: 0..3 edge, 4..5 coord

    for (int b = 0; b < 2; ++b) {
        const float* x_old;
        float*       x_new;
        const float* radp;
        if (b == 0) {
            x_old = x_in;  x_new = xA;    radp = d0S;
        } else {
            x_old = xA;    x_new = out_x; radp = radS;
            k_radial<<<eb, th, 0, stream>>>(x_old, rowS, colS, radS);
        }
        for (int i = 0; i < 2; ++i) {
            int l = b*2 + i;
            k_pq<<<t64b, th, 0, stream>>>(h64, pqf + (size_t)l*8192,
                                          e_b1 + (size_t)l*64, Pb, Qb);
            hipMemsetAsync(agg, 0, (size_t)NN*64*sizeof(float), stream);
            k_edge<<<eb, th, 0, stream>>>(Pb, Qb, radp, d0S, rowS, colS,
                    e_w1 + (size_t)l*130*64 + 128*64,
                    wf + (size_t)l*4096,
                    e_b2 + (size_t)l*64, agg);
            k_node<<<t64b, th, 0, stream>>>(h64, agg,
                    nw1f + (size_t)l*8192, n_b1 + (size_t)l*64,
                    nw2f + (size_t)l*4096, n_b2 + (size_t)l*64);
        }
        k_pq<<<t64b, th, 0, stream>>>(h64, pqf + (size_t)(4 + b)*8192,
                                      q_b1 + (size_t)b*64, Pb, Qb);
        hipMemcpyAsync(x_new, x_old, (size_t)NN*3*sizeof(float),
                       hipMemcpyDeviceToDevice, stream);
        k_coord<<<eb, th, 0, stream>>>(Pb, Qb, radp, d0S, rowS, colS,
                q_w1 + (size_t)b*130*64 + 128*64,
                wf + (size_t)(4 + b)*4096,
                q_b2 + (size_t)b*64, q_w3 + (size_t)b*64, x_old, x_new);
    }
    k_out<<<nb, th, 0, stream>>>(h64, out_w, out_b, out_h);
}

// Round 8
// 839.013 us; speedup vs baseline: 2.5215x; 1.0489x over previous
//
#include <hip/hip_runtime.h>

#define NN 50000
#define NE 800000

typedef unsigned int  u32;
typedef unsigned short u16;
typedef __attribute__((ext_vector_type(8))) short short8;
typedef __attribute__((ext_vector_type(4))) float f32x4;

union ABfrag { uint2 u2[2]; uint4 u4; short8 s8; };

__device__ __forceinline__ float silu_f(float v) {
    return v * (1.0f / (1.0f + __expf(-v)));
}
// cheap bf16 pair pack (round-half-up): 2 adds + 1 v_perm
__device__ __forceinline__ u32 pk2(float lo, float hi) {
    return __builtin_amdgcn_perm(__float_as_uint(hi) + 0x8000u,
                                 __float_as_uint(lo) + 0x8000u, 0x07060302u);
}
__device__ __forceinline__ float bff(u32 h) { return __uint_as_float(h << 16); }

// ---------------- embedding: h64 = h @ emb_w + emb_b  (N x 16 -> N x 64)
__global__ __launch_bounds__(256, 4) void k_embed(const float* __restrict__ h,
        const float* __restrict__ w, const float* __restrict__ b,
        float* __restrict__ h64) {
    int n = blockIdx.x * 256 + threadIdx.x;
    if (n >= NN) return;
    const float4* h4 = (const float4*)(h + (long)n * 16);
    float in[16];
    #pragma unroll
    for (int c = 0; c < 4; ++c) {
        float4 v = h4[c];
        in[4*c+0] = v.x; in[4*c+1] = v.y; in[4*c+2] = v.z; in[4*c+3] = v.w;
    }
    float acc[64];
    #pragma unroll
    for (int j = 0; j < 64; ++j) acc[j] = b[j];
    #pragma unroll
    for (int k = 0; k < 16; ++k) {
        #pragma unroll
        for (int j = 0; j < 64; ++j) acc[j] = fmaf(in[k], w[k*64 + j], acc[j]);
    }
    float4* o4 = (float4*)(h64 + (long)n * 64);
    #pragma unroll
    for (int c = 0; c < 16; ++c)
        o4[c] = make_float4(acc[4*c+0], acc[4*c+1], acc[4*c+2], acc[4*c+3]);
}

// ---------------- CSR-order build ----------------
__global__ __launch_bounds__(256, 4) void k_hist(const int* __restrict__ row,
        int* __restrict__ deg) {
    int e = blockIdx.x * 256 + threadIdx.x;
    if (e < NE) atomicAdd(&deg[row[e]], 1);
}

__global__ __launch_bounds__(256) void k_scan(const int* __restrict__ deg,
        int* __restrict__ base) {
    __shared__ int s[256];
    const int CH = (NN + 255) / 256;
    int t = threadIdx.x;
    int lo = t * CH, hi = min(lo + CH, NN);
    int sum = 0;
    for (int i = lo; i < hi; ++i) sum += deg[i];
    s[t] = sum;
    __syncthreads();
    #pragma unroll
    for (int d = 1; d < 256; d <<= 1) {
        int v = (t >= d) ? s[t - d] : 0;
        __syncthreads();
        s[t] += v;
        __syncthreads();
    }
    int run = s[t] - sum;
    for (int i = lo; i < hi; ++i) { base[i] = run; run += deg[i]; }
}

__global__ __launch_bounds__(256, 4) void k_scatter(const int* __restrict__ row,
        const int* __restrict__ col, int* __restrict__ base,
        int* __restrict__ rowS, int* __restrict__ colS) {
    int e = blockIdx.x * 256 + threadIdx.x;
    if (e >= NE) return;
    int r = row[e];
    int p = atomicAdd(&base[r], 1);
    rowS[p] = r;
    colS[p] = col[e];
}

// ---------------- per-edge squared distance (sorted edge space)
__global__ __launch_bounds__(256, 4) void k_radial(const float* __restrict__ x,
        const int* __restrict__ rowS, const int* __restrict__ colS,
        float* __restrict__ radial) {
    int e = blockIdx.x * 256 + threadIdx.x;
    if (e >= NE) return;
    int r = rowS[e], c = colS[e];
    float dx = x[r*3+0] - x[c*3+0];
    float dy = x[r*3+1] - x[c*3+1];
    float dz = x[r*3+2] - x[c*3+2];
    radial[e] = dx*dx + dy*dy + dz*dz;
}

// ---------------- weight -> bf16 B-fragment tables (RNE here, one-time)
__device__ __forceinline__ u32 bfr_rne(float x) {
    u32 u = __float_as_uint(x);
    u += 0x7fffu + ((u >> 16) & 1u);
    return u >> 16;
}
__global__ __launch_bounds__(256, 4) void k_wconv(const float* __restrict__ e_w2,
        const float* __restrict__ q_w2, const float* __restrict__ n_w1,
        const float* __restrict__ n_w2, const float* __restrict__ e_w1,
        const float* __restrict__ q_w1, u16* __restrict__ wf) {
    int t = blockIdx.x * 256 + threadIdx.x;
    if (t >= 122880) return;
    int j, lane, n, s, k, col;
    if (t < 24576) {
        int L = t >> 12, v = t & 4095;
        j = v & 7; lane = (v >> 3) & 63; int ns = v >> 9; n = ns >> 1; s = ns & 1;
        k = 8*(lane >> 4) + j + 32*s;
        col = 16*n + (lane & 15);
        const float* src = (L < 4) ? e_w2 + (size_t)L*4096 : q_w2 + (size_t)(L-4)*4096;
        wf[t] = (u16)bfr_rne(src[k*64 + col]);
    } else if (t < 57344) {
        int u = t - 24576; int L = u >> 13, v = u & 8191;
        j = v & 7; lane = (v >> 3) & 63; int ns = v >> 9; n = ns >> 2; s = ns & 3;
        k = 8*(lane >> 4) + j + 32*s;
        col = 16*n + (lane & 15);
        wf[t] = (u16)bfr_rne(n_w1[(size_t)L*8192 + k*64 + col]);
    } else if (t < 73728) {
        int u = t - 57344; int L = u >> 12, v = u & 4095;
        j = v & 7; lane = (v >> 3) & 63; int ns = v >> 9; n = ns >> 1; s = ns & 1;
        k = 8*(lane >> 4) + j + 32*s;
        col = 16*n + (lane & 15);
        wf[t] = (u16)bfr_rne(n_w2[(size_t)L*4096 + k*64 + col]);
    } else {
        int u = t - 73728;
        int L = u >> 13;
        int v = u & 8191;
        int m = v >> 12;
        int v2 = v & 4095;
        j = v2 & 7; lane = (v2 >> 3) & 63; int ns = v2 >> 9; n = ns >> 1; s = ns & 1;
        k = 8*(lane >> 4) + j + 32*s;
        col = 16*n + (lane & 15);
        const float* src = (L < 4) ? e_w1 + (size_t)L*130*64
                                   : q_w1 + (size_t)(L-4)*130*64;
        wf[t] = (u16)bfr_rne(src[(size_t)(m*64 + k)*64 + col]);
    }
}

// ---------------- standalone P/Q via MFMA (layers l0, l2 only)
__global__ __launch_bounds__(256, 4) void k_pq(const float* __restrict__ h64,
        const u16* __restrict__ wpf, const float* __restrict__ b1,
        u32* __restrict__ Pb, u32* __restrict__ Qb) {
    __shared__ u16 A[64*64];
    __shared__ u16 XP[64*68], XQ[64*68];
    int t = threadIdx.x, w = t >> 6, lane = t & 63;
    int nb0 = blockIdx.x * 64;
    #pragma unroll
    for (int i = 0; i < 4; ++i) {
        int idx = i*256 + t;
        int r = idx >> 4, c = idx & 15;
        int n = nb0 + r;
        float4 v = make_float4(0.f, 0.f, 0.f, 0.f);
        if (n < NN) v = ((const float4*)(h64 + (size_t)n*64))[c];
        uint2 pk = make_uint2(pk2(v.x, v.y), pk2(v.z, v.w));
        *(uint2*)((char*)A + r*128 + ((8*c) ^ ((r & 15) << 3))) = pk;
    }
    __syncthreads();
    int r0 = lane & 15, g = lane >> 4;
    ABfrag bp[2], bq[2];
    #pragma unroll
    for (int s = 0; s < 2; ++s) {
        bp[s].u4 = *(const uint4*)(wpf + ((size_t)(w*2 + s)*64 + lane)*8);
        bq[s].u4 = *(const uint4*)(wpf + 4096 + ((size_t)(w*2 + s)*64 + lane)*8);
    }
    f32x4 aP[4], aQ[4];
    #pragma unroll
    for (int t4 = 0; t4 < 4; ++t4) {
        aP[t4] = (f32x4){0.f, 0.f, 0.f, 0.f};
        aQ[t4] = (f32x4){0.f, 0.f, 0.f, 0.f};
    }
    #pragma unroll
    for (int t4 = 0; t4 < 4; ++t4) {
        #pragma unroll
        for (int s = 0; s < 2; ++s) {
            int boff = 16*g + 64*s;
            ABfrag af;
            af.u2[0] = *(uint2*)((char*)A + (16*t4 + r0)*128 + ( boff      ^ (r0 << 3)));
            af.u2[1] = *(uint2*)((char*)A + (16*t4 + r0)*128 + ((boff + 8) ^ (r0 << 3)));
            aP[t4] = __builtin_amdgcn_mfma_f32_16x16x32_bf16(af.s8, bp[s].s8, aP[t4], 0, 0, 0);
            aQ[t4] = __builtin_amdgcn_mfma_f32_16x16x32_bf16(af.s8, bq[s].s8, aQ[t4], 0, 0, 0);
        }
    }
    float bv = b1[16*w + r0];
    #pragma unroll
    for (int t4 = 0; t4 < 4; ++t4)
        #pragma unroll
        for (int q = 0; q < 4; ++q) {
            int rw = 16*t4 + 4*g + q;
            XP[rw*68 + 16*w + r0] = (u16)(pk2(aP[t4][q] + bv, 0.f) & 0xffffu);
            XQ[rw*68 + 16*w + r0] = (u16)(pk2(aQ[t4][q], 0.f) & 0xffffu);
        }
    __syncthreads();
    int node = t >> 2, part = t & 3;
    if (nb0 + node < NN) {
        const u32* XPw = (const u32*)XP;
        const u32* XQw = (const u32*)XQ;
        u32 b[8];
        #pragma unroll
        for (int j = 0; j < 8; ++j) b[j] = XPw[node*34 + 8*part + j];
        uint4* dp = (uint4*)(Pb + (size_t)(nb0 + node)*32 + part*8);
        dp[0] = make_uint4(b[0], b[1], b[2], b[3]);
        dp[1] = make_uint4(b[4], b[5], b[6], b[7]);
        #pragma unroll
        for (int j = 0; j < 8; ++j) b[j] = XQw[node*34 + 8*part + j];
        uint4* dq = (uint4*)(Qb + (size_t)(nb0 + node)*32 + part*8);
        dq[0] = make_uint4(b[0], b[1], b[2], b[3]);
        dq[1] = make_uint4(b[4], b[5], b[6], b[7]);
    }
}

// ---------------- edge MLP: uint4 gathers, pk2 packs, ballot/readlane agg
__global__ __launch_bounds__(256, 4) void k_edge(
        const u32* __restrict__ Pb, const u32* __restrict__ Qb,
        const float* __restrict__ radial, const float* __restrict__ dist0,
        const int* __restrict__ rowS, const int* __restrict__ colS,
        const float* __restrict__ w1t, const u16* __restrict__ w2f,
        const float* __restrict__ b2, float* __restrict__ agg) {
    __shared__ u16 S_lds[4][4224];   // union: A [64][64] / M [64f][66e]
    int tid = threadIdx.x;
    int w = tid >> 6, lane = tid & 63;
    int e = blockIdx.x * 256 + w * 64 + lane;
    u16* Aw = S_lds[w];
    int r = rowS[e], c = colS[e];
    float rad = radial[e], d0 = dist0[e];
    const uint4* Pr = (const uint4*)(Pb + (size_t)r * 32);
    const uint4* Qc = (const uint4*)(Qb + (size_t)c * 32);
    int swz = (lane & 15) << 3;
    #pragma unroll
    for (int c8 = 0; c8 < 8; ++c8) {
        uint4 pu = Pr[c8], qu = Qc[c8];
        u32 pw[4] = {pu.x, pu.y, pu.z, pu.w};
        u32 qw[4] = {qu.x, qu.y, qu.z, qu.w};
        float hv[8];
        #pragma unroll
        for (int k2 = 0; k2 < 4; ++k2) {
            int f = 8*c8 + 2*k2;
            float pl = bff(pw[k2] & 0xffffu), ph = bff(pw[k2] >> 16);
            float ql = bff(qw[k2] & 0xffffu), qh = bff(qw[k2] >> 16);
            hv[2*k2]   = silu_f(pl + ql + rad*w1t[f]     + d0*w1t[64+f]);
            hv[2*k2+1] = silu_f(ph + qh + rad*w1t[f+1]   + d0*w1t[64+f+1]);
        }
        uint2 pkA = make_uint2(pk2(hv[0], hv[1]), pk2(hv[2], hv[3]));
        uint2 pkB = make_uint2(pk2(hv[4], hv[5]), pk2(hv[6], hv[7]));
        *(uint2*)((char*)Aw + lane*128 + ((16*c8)     ^ swz)) = pkA;
        *(uint2*)((char*)Aw + lane*128 + ((16*c8 + 8) ^ swz)) = pkB;
    }
    __syncthreads();
    ABfrag bf[4][2];
    #pragma unroll
    for (int n = 0; n < 4; ++n)
        #pragma unroll
        for (int s = 0; s < 2; ++s)
            bf[n][s].u4 = *(const uint4*)(w2f + ((n*2 + s)*64 + lane)*8);
    int r0 = lane & 15, g = lane >> 4;
    f32x4 acc[4][4];
    #pragma unroll
    for (int t = 0; t < 4; ++t)
        #pragma unroll
        for (int n = 0; n < 4; ++n)
            acc[t][n] = (f32x4){0.f, 0.f, 0.f, 0.f};
    #pragma unroll
    for (int t = 0; t < 4; ++t) {
        #pragma unroll
        for (int s = 0; s < 2; ++s) {
            int boff = 16*g + 64*s;
            ABfrag af;
            af.u2[0] = *(uint2*)((char*)Aw + (16*t + r0)*128 + ( boff      ^ (r0 << 3)));
            af.u2[1] = *(uint2*)((char*)Aw + (16*t + r0)*128 + ((boff + 8) ^ (r0 << 3)));
            #pragma unroll
            for (int n = 0; n < 4; ++n)
                acc[t][n] = __builtin_amdgcn_mfma_f32_16x16x32_bf16(
                    af.s8, bf[n][s].s8, acc[t][n], 0, 0, 0);
        }
    }
    __syncthreads();
    u16* Mw = Aw;      // overlay: [64 feat][66 edge], row stride 132 B
    #pragma unroll
    for (int n = 0; n < 4; ++n) {
        float b2v = b2[16*n + r0];
        #pragma unroll
        for (int t = 0; t < 4; ++t) {
            f32x4 z = acc[t][n];
            u32 p0 = pk2(silu_f(z[0] + b2v), silu_f(z[1] + b2v));
            u32 p1 = pk2(silu_f(z[2] + b2v), silu_f(z[3] + b2v));
            *(uint2*)((char*)Mw + (16*n + r0)*132 + 32*t + 8*g) = make_uint2(p0, p1);
        }
    }
    __syncthreads();
    // run-tail mask once (wave-uniform, lives in SGPRs)
    int rnext = __shfl_down(r, 1);
    unsigned long long tm = __ballot((lane == 63) || (rnext != r));
    float racc = 0.0f;
    #pragma unroll
    for (int ch = 0; ch < 16; ++ch) {
        uint2 mm = *(uint2*)((char*)Mw + lane*132 + 8*ch);
        u32 mw[2] = {mm.x, mm.y};
        #pragma unroll
        for (int q = 0; q < 4; ++q) {
            int ee = 4*ch + q;
            racc += bff((mw[q >> 1] >> ((q & 1) * 16)) & 0xffffu);
            if ((tm >> ee) & 1ull) {
                int rr = __builtin_amdgcn_readlane(r, ee);
                atomicAdd(&agg[(size_t)rr*64 + lane], racc);
                racc = 0.0f;
            }
        }
    }
}

// ---------------- fused node MLP + next-layer P/Q (all MFMA)
__global__ __launch_bounds__(256, 3) void k_node_pq(float* __restrict__ h64,
        const float* __restrict__ agg,
        const u16* __restrict__ w1f, const float* __restrict__ b1,
        const u16* __restrict__ w2f, const float* __restrict__ b2,
        const u16* __restrict__ wpf, const float* __restrict__ b1pq,
        u32* __restrict__ Pb, u32* __restrict__ Qb) {
    __shared__ u16 S[16512];
    u16* A0 = S;             // 4096 u16: k 0..63 (h), swizzled
    u16* A1 = S + 4096;      // k 64..127 (agg*0.01)
    u16* H  = S + 8192;      // hidden
    u16* D  = S + 12288;     // delta [node][66]
    u16* An = S;             // phase2: new-h A-tile (overlays A0)
    u16* XPh = S + 4096;     // phase2: [node][68]
    u16* XQh = S + 8448;
    int t = threadIdx.x, w = t >> 6, lane = t & 63;
    int nb0 = blockIdx.x * 64;
    #pragma unroll
    for (int i = 0; i < 8; ++i) {
        int idx = i*256 + t;
        int r = idx >> 5, c = idx & 31;
        int n = nb0 + r;
        float4 v = make_float4(0.f, 0.f, 0.f, 0.f);
        if (n < NN) {
            if (c < 16) v = ((const float4*)(h64 + (size_t)n*64))[c];
            else {
                float4 a = ((const float4*)(agg + (size_t)n*64))[c-16];
                v = make_float4(a.x*0.01f, a.y*0.01f, a.z*0.01f, a.w*0.01f);
            }
        }
        uint2 pk = make_uint2(pk2(v.x, v.y), pk2(v.z, v.w));
        u16* dst = (c < 16) ? A0 : A1;
        int cc = c & 15;
        *(uint2*)((char*)dst + r*128 + ((8*cc) ^ ((r & 15) << 3))) = pk;
    }
    __syncthreads();
    int r0 = lane & 15, g = lane >> 4;
    ABfrag bf1[4];
    #pragma unroll
    for (int s = 0; s < 4; ++s)
        bf1[s].u4 = *(const uint4*)(w1f + ((size_t)(w*4 + s)*64 + lane)*8);
    f32x4 acc[4];
    #pragma unroll
    for (int t4 = 0; t4 < 4; ++t4) acc[t4] = (f32x4){0.f, 0.f, 0.f, 0.f};
    #pragma unroll
    for (int t4 = 0; t4 < 4; ++t4) {
        #pragma unroll
        for (int s = 0; s < 4; ++s) {
            const u16* Ah = (s < 2) ? A0 : A1;
            int boff = 16*g + 64*(s & 1);
            ABfrag af;
            af.u2[0] = *(uint2*)((char*)Ah + (16*t4 + r0)*128 + ( boff      ^ (r0 << 3)));
            af.u2[1] = *(uint2*)((char*)Ah + (16*t4 + r0)*128 + ((boff + 8) ^ (r0 << 3)));
            acc[t4] = __builtin_amdgcn_mfma_f32_16x16x32_bf16(
                af.s8, bf1[s].s8, acc[t4], 0, 0, 0);
        }
    }
    float b1v = b1[16*w + r0];
    #pragma unroll
    for (int t4 = 0; t4 < 4; ++t4)
        #pragma unroll
        for (int q = 0; q < 4; ++q) {
            int rw = 16*t4 + 4*g + q;
            u16 hv = (u16)(pk2(silu_f(acc[t4][q] + b1v), 0.f) & 0xffffu);
            *(u16*)((char*)H + rw*128 + ((2*(16*w + r0)) ^ ((rw & 15) << 3))) = hv;
        }
    __syncthreads();
    ABfrag bf2[2];
    #pragma unroll
    for (int s = 0; s < 2; ++s)
        bf2[s].u4 = *(const uint4*)(w2f + ((size_t)(w*2 + s)*64 + lane)*8);
    f32x4 acc2[4];
    #pragma unroll
    for (int t4 = 0; t4 < 4; ++t4) acc2[t4] = (f32x4){0.f, 0.f, 0.f, 0.f};
    #pragma unroll
    for (int t4 = 0; t4 < 4; ++t4) {
        #pragma unroll
        for (int s = 0; s < 2; ++s) {
            int boff = 16*g + 64*s;
            ABfrag af;
            af.u2[0] = *(uint2*)((char*)H + (16*t4 + r0)*128 + ( boff      ^ (r0 << 3)));
            af.u2[1] = *(uint2*)((char*)H + (16*t4 + r0)*128 + ((boff + 8) ^ (r0 << 3)));
            acc2[t4] = __builtin_amdgcn_mfma_f32_16x16x32_bf16(
                af.s8, bf2[s].s8, acc2[t4], 0, 0, 0);
        }
    }
    float b2v = b2[16*w + r0];
    #pragma unroll
    for (int t4 = 0; t4 < 4; ++t4)
        #pragma unroll
        for (int q = 0; q < 4; ++q) {
            int rw = 16*t4 + 4*g + q;
            D[rw*66 + 16*w + r0] = (u16)(pk2(acc2[t4][q] + b2v, 0.f) & 0xffffu);
        }
    __syncthreads();
    // residual RMW (coalesced) + build new-h A-tile for the fused P/Q
    #pragma unroll
    for (int i = 0; i < 4; ++i) {
        int idx = i*256 + t;
        int rr = idx >> 4, cc = idx & 15;
        int n = nb0 + rr;
        float4 v = make_float4(0.f, 0.f, 0.f, 0.f);
        if (n < NN) {
            v = ((const float4*)(h64 + (size_t)n*64))[cc];
            v.x += bff(D[rr*66 + 4*cc + 0]);
            v.y += bff(D[rr*66 + 4*cc + 1]);
            v.z += bff(D[rr*66 + 4*cc + 2]);
            v.w += bff(D[rr*66 + 4*cc + 3]);
            ((float4*)(h64 + (size_t)n*64))[cc] = v;
        }
        uint2 pk = make_uint2(pk2(v.x, v.y), pk2(v.z, v.w));
        *(uint2*)((char*)An + rr*128 + ((8*cc) ^ ((rr & 15) << 3))) = pk;
    }
    __syncthreads();
    // ---- fused P/Q
    ABfrag bp[2], bq[2];
    #pragma unroll
    for (int s = 0; s < 2; ++s) {
        bp[s].u4 = *(const uint4*)(wpf + ((size_t)(w*2 + s)*64 + lane)*8);
        bq[s].u4 = *(const uint4*)(wpf + 4096 + ((size_t)(w*2 + s)*64 + lane)*8);
    }
    f32x4 aP[4], aQ[4];
    #pragma unroll
    for (int t4 = 0; t4 < 4; ++t4) {
        aP[t4] = (f32x4){0.f, 0.f, 0.f, 0.f};
        aQ[t4] = (f32x4){0.f, 0.f, 0.f, 0.f};
    }
    #pragma unroll
    for (int t4 = 0; t4 < 4; ++t4) {
        #pragma unroll
        for (int s = 0; s < 2; ++s) {
            int boff = 16*g + 64*s;
            ABfrag af;
            af.u2[0] = *(uint2*)((char*)An + (16*t4 + r0)*128 + ( boff      ^ (r0 << 3)));
            af.u2[1] = *(uint2*)((char*)An + (16*t4 + r0)*128 + ((boff + 8) ^ (r0 << 3)));
            aP[t4] = __builtin_amdgcn_mfma_f32_16x16x32_bf16(af.s8, bp[s].s8, aP[t4], 0, 0, 0);
            aQ[t4] = __builtin_amdgcn_mfma_f32_16x16x32_bf16(af.s8, bq[s].s8, aQ[t4], 0, 0, 0);
        }
    }
    float bv = b1pq[16*w + r0];
    #pragma unroll
    for (int t4 = 0; t4 < 4; ++t4)
        #pragma unroll
        for (int q = 0; q < 4; ++q) {
            int rw = 16*t4 + 4*g + q;
            XPh[rw*68 + 16*w + r0] = (u16)(pk2(aP[t4][q] + bv, 0.f) & 0xffffu);
            XQh[rw*68 + 16*w + r0] = (u16)(pk2(aQ[t4][q], 0.f) & 0xffffu);
        }
    __syncthreads();
    int node = t >> 2, part = t & 3;
    if (nb0 + node < NN) {
        const u32* XPw = (const u32*)XPh;
        const u32* XQw = (const u32*)XQh;
        u32 b[8];
        #pragma unroll
        for (int j = 0; j < 8; ++j) b[j] = XPw[node*34 + 8*part + j];
        uint4* dp = (uint4*)(Pb + (size_t)(nb0 + node)*32 + part*8);
        dp[0] = make_uint4(b[0], b[1], b[2], b[3]);
        dp[1] = make_uint4(b[4], b[5], b[6], b[7]);
        #pragma unroll
        for (int j = 0; j < 8; ++j) b[j] = XQw[node*34 + 8*part + j];
        uint4* dq = (uint4*)(Qb + (size_t)(nb0 + node)*32 + part*8);
        dq[0] = make_uint4(b[0], b[1], b[2], b[3]);
        dq[1] = make_uint4(b[4], b[5], b[6], b[7]);
    }
}

// ---------------- coordinate update: MFMA layer2, LDS phi reduction
__global__ __launch_bounds__(256, 4) void k_coord(
        const u32* __restrict__ Pb, const u32* __restrict__ Qb,
        const float* __restrict__ radial, const float* __restrict__ dist0,
        const int* __restrict__ rowS, const int* __restrict__ colS,
        const float* __restrict__ w1t, const u16* __restrict__ w2f,
        const float* __restrict__ b2, const float* __restrict__ w3,
        const float* __restrict__ x_old, float* __restrict__ x_new) {
    __shared__ u16 A_lds[4][4096];
    int tid = threadIdx.x;
    int w = tid >> 6, lane = tid & 63;
    int e = blockIdx.x * 256 + w * 64 + lane;
    u16* Aw = A_lds[w];
    int r = rowS[e], c = colS[e];
    float rad = radial[e], d0 = dist0[e];
    const uint4* Pr = (const uint4*)(Pb + (size_t)r * 32);
    const uint4* Qc = (const uint4*)(Qb + (size_t)c * 32);
    int swz = (lane & 15) << 3;
    #pragma unroll
    for (int c8 = 0; c8 < 8; ++c8) {
        uint4 pu = Pr[c8], qu = Qc[c8];
        u32 pw[4] = {pu.x, pu.y, pu.z, pu.w};
        u32 qw[4] = {qu.x, qu.y, qu.z, qu.w};
        float hv[8];
        #pragma unroll
        for (int k2 = 0; k2 < 4; ++k2) {
            int f = 8*c8 + 2*k2;
            float pl = bff(pw[k2] & 0xffffu), ph = bff(pw[k2] >> 16);
            float ql = bff(qw[k2] & 0xffffu), qh = bff(qw[k2] >> 16);
            hv[2*k2]   = silu_f(pl + ql + rad*w1t[f]   + d0*w1t[64+f]);
            hv[2*k2+1] = silu_f(ph + qh + rad*w1t[f+1] + d0*w1t[64+f+1]);
        }
        uint2 pkA = make_uint2(pk2(hv[0], hv[1]), pk2(hv[2], hv[3]));
        uint2 pkB = make_uint2(pk2(hv[4], hv[5]), pk2(hv[6], hv[7]));
        *(uint2*)((char*)Aw + lane*128 + ((16*c8)     ^ swz)) = pkA;
        *(uint2*)((char*)Aw + lane*128 + ((16*c8 + 8) ^ swz)) = pkB;
    }
    __syncthreads();
    ABfrag bf[4][2];
    #pragma unroll
    for (int n = 0; n < 4; ++n)
        #pragma unroll
        for (int s = 0; s < 2; ++s)
            bf[n][s].u4 = *(const uint4*)(w2f + ((n*2 + s)*64 + lane)*8);
    int r0 = lane & 15, g = lane >> 4;
    f32x4 acc[4][4];
    #pragma unroll
    for (int t = 0; t < 4; ++t)
        #pragma unroll
        for (int n = 0; n < 4; ++n)
            acc[t][n] = (f32x4){0.f, 0.f, 0.f, 0.f};
    #pragma unroll
    for (int t = 0; t < 4; ++t) {
        #pragma unroll
        for (int s = 0; s < 2; ++s) {
            int boff = 16*g + 64*s;
            ABfrag af;
            af.u2[0] = *(uint2*)((char*)Aw + (16*t + r0)*128 + ( boff      ^ (r0 << 3)));
            af.u2[1] = *(uint2*)((char*)Aw + (16*t + r0)*128 + ((boff + 8) ^ (r0 << 3)));
            #pragma unroll
            for (int n = 0; n < 4; ++n)
                acc[t][n] = __builtin_amdgcn_mfma_f32_16x16x32_bf16(
                    af.s8, bf[n][s].s8, acc[t][n], 0, 0, 0);
        }
    }
    float w3v[4], b2v[4];
    #pragma unroll
    for (int n = 0; n < 4; ++n) { w3v[n] = w3[16*n + r0]; b2v[n] = b2[16*n + r0]; }
    float ph[16];
    #pragma unroll
    for (int t = 0; t < 4; ++t)
        #pragma unroll
        for (int q = 0; q < 4; ++q) {
            float s = 0.f;
            #pragma unroll
            for (int n = 0; n < 4; ++n)
                s = fmaf(silu_f(acc[t][n][q] + b2v[n]), w3v[n], s);
            ph[t*4 + q] = s;
        }
    __syncthreads();                 // A reads done; overlay phi matrix
    float* Mw = (float*)Aw;          // [64 rows][17] f32 (4.25 KB < 8 KB)
    #pragma unroll
    for (int t4 = 0; t4 < 4; ++t4)
        #pragma unroll
        for (int q = 0; q < 4; ++q)
            Mw[(16*t4 + 4*g + q)*17 + r0] = ph[t4*4 + q];
    __syncthreads();
    float phi = 0.f;
    #pragma unroll
    for (int i = 0; i < 16; ++i) phi += Mw[lane*17 + i];
    phi *= 0.01f;
    float dx = x_old[r*3+0] - x_old[c*3+0];
    float dy = x_old[r*3+1] - x_old[c*3+1];
    float dz = x_old[r*3+2] - x_old[c*3+2];
    float inv = phi / (sqrtf(rad + 1e-8f) + 1.0f);
    float tx = dx * inv, ty = dy * inv, tz = dz * inv;
    int rprev = __shfl_up(r, 1);
    bool head = (lane == 0) || (rprev != r);
    unsigned long long hm = __ballot(head);
    int runid = __popcll(hm & ((2ull << lane) - 1ull));
    #pragma unroll
    for (int d = 1; d < 64; d <<= 1) {
        float ox = __shfl_up(tx, d);
        float oy = __shfl_up(ty, d);
        float oz = __shfl_up(tz, d);
        int orid = __shfl_up(runid, d);
        if (lane >= d && orid == runid) { tx += ox; ty += oy; tz += oz; }
    }
    int rid_next = __shfl_down(runid, 1);
    bool tail = (lane == 63) || (rid_next != runid);
    if (tail) {
        atomicAdd(&x_new[r*3+0], tx);
        atomicAdd(&x_new[r*3+1], ty);
        atomicAdd(&x_new[r*3+2], tz);
    }
}

// ---------------- output projection
__global__ __launch_bounds__(256, 4) void k_out(const float* __restrict__ h64,
        const float* __restrict__ w, const float* __restrict__ b,
        float* __restrict__ out) {
    int n = blockIdx.x * 256 + threadIdx.x;
    if (n >= NN) return;
    float acc[16];
    #pragma unroll
    for (int j = 0; j < 16; ++j) acc[j] = b[j];
    const float4* h4 = (const float4*)(h64 + (long)n*64);
    #pragma unroll
    for (int c = 0; c < 16; ++c) {
        float4 v = h4[c];
        float vv[4] = {v.x, v.y, v.z, v.w};
        #pragma unroll
        for (int t = 0; t < 4; ++t) {
            #pragma unroll
            for (int j = 0; j < 16; ++j)
                acc[j] = fmaf(vv[t], w[(4*c+t)*16 + j], acc[j]);
        }
    }
    float4* o4 = (float4*)(out + (long)n*16);
    #pragma unroll
    for (int cq = 0; cq < 4; ++cq)
        o4[cq] = make_float4(acc[4*cq+0],acc[4*cq+1],acc[4*cq+2],acc[4*cq+3]);
}

extern "C" void kernel_launch(void* const* d_in, const int* in_sizes, int n_in,
                              void* d_out, int out_size, void* d_ws, size_t ws_size,
                              hipStream_t stream) {
    const float* h_in  = (const float*)d_in[0];
    const float* x_in  = (const float*)d_in[1];
    const int*   row   = (const int*)d_in[2];
    const int*   col   = (const int*)d_in[3];
    const float* emb_w = (const float*)d_in[4];
    const float* emb_b = (const float*)d_in[5];
    const float* out_w = (const float*)d_in[6];
    const float* out_b = (const float*)d_in[7];
    const float* e_w1  = (const float*)d_in[8];
    const float* e_b1  = (const float*)d_in[9];
    const float* e_w2  = (const float*)d_in[10];
    const float* e_b2  = (const float*)d_in[11];
    const float* n_w1  = (const float*)d_in[12];
    const float* n_b1  = (const float*)d_in[13];
    const float* n_w2  = (const float*)d_in[14];
    const float* n_b2  = (const float*)d_in[15];
    const float* q_w1  = (const float*)d_in[16];
    const float* q_b1  = (const float*)d_in[17];
    const float* q_w2  = (const float*)d_in[18];
    const float* q_b2  = (const float*)d_in[19];
    const float* q_w3  = (const float*)d_in[20];

    const size_t WF_N = 122880;
    const size_t WF_BYTES = WF_N * sizeof(u16);
    size_t need = WF_BYTES + ((size_t)NN*64*4 + (size_t)NE*2 + (size_t)NN*3
                   + (size_t)NE*2 + (size_t)NN*2 + 64) * sizeof(float);
    if (ws_size < need) return;

    u16*   wf    = (u16*)d_ws;
    float* fb    = (float*)((char*)d_ws + WF_BYTES);
    float* h64   = fb;
    u32*   Pb    = (u32*)(h64 + (size_t)NN*64);
    u32*   Qb    = Pb + (size_t)NN*32;
    float* agg   = (float*)(Qb + (size_t)NN*32);
    float* d0S   = agg   + (size_t)NN*64;
    float* radS  = d0S   + (size_t)NE;
    float* xA    = radS  + (size_t)NE;
    int*   rowS  = (int*)(xA + (size_t)NN*3);
    int*   colS  = rowS  + (size_t)NE;
    int*   deg   = colS  + (size_t)NE;
    int*   base  = deg   + (size_t)NN;

    float* out_h = (float*)d_out;
    float* out_x = out_h + (size_t)NN*16;

    dim3 th(256);
    dim3 nb((NN + 255)/256);
    dim3 eb(NE/256);
    dim3 t64b((NN + 63)/64);

    hipMemsetAsync(deg, 0, (size_t)NN*sizeof(int), stream);
    k_hist<<<eb, th, 0, stream>>>(row, deg);
    k_scan<<<1, th, 0, stream>>>(deg, base);
    k_scatter<<<eb, th, 0, stream>>>(row, col, base, rowS, colS);
    k_wconv<<<480, th, 0, stream>>>(e_w2, q_w2, n_w1, n_w2, e_w1, q_w1, wf);

    k_radial<<<eb, th, 0, stream>>>(x_in, rowS, colS, d0S);
    k_embed<<<nb, th, 0, stream>>>(h_in, emb_w, emb_b, h64);

    const u16* nw1f = wf + 24576;
    const u16* nw2f = wf + 57344;
    const u16* pqf  = wf + 73728;   // + L*8192, L: 0..3 edge, 4..5 coord

    for (int b = 0; b < 2; ++b) {
        const float* x_old;
        float*       x_new;
        const float* radp;
        if (b == 0) {
            x_old = x_in;  x_new = xA;    radp = d0S;
        } else {
            x_old = xA;    x_new = out_x; radp = radS;
            k_radial<<<eb, th, 0, stream>>>(x_old, rowS, colS, radS);
        }
        for (int i = 0; i < 2; ++i) {
            int l = b*2 + i;
            if (i == 0)   // P/Q for l0 / l2 produced standalone; l1,l3,q via fusion
                k_pq<<<t64b, th, 0, stream>>>(h64, pqf + (size_t)l*8192,
                                              e_b1 + (size_t)l*64, Pb, Qb);
            hipMemsetAsync(agg, 0, (size_t)NN*64*sizeof(float), stream);
            k_edge<<<eb, th, 0, stream>>>(Pb, Qb, radp, d0S, rowS, colS,
                    e_w1 + (size_t)l*130*64 + 128*64,
                    wf + (size_t)l*4096,
                    e_b2 + (size_t)l*64, agg);
            // fused node + next P/Q: (l even) -> edge layer l+1 ; (l odd) -> coord q_b
            const u16* nxt_f  = (i == 0) ? pqf + (size_t)(l+1)*8192
                                         : pqf + (size_t)(4 + b)*8192;
            const float* nxt_b = (i == 0) ? e_b1 + (size_t)(l+1)*64
                                          : q_b1 + (size_t)b*64;
            k_node_pq<<<t64b, th, 0, stream>>>(h64, agg,
                    nw1f + (size_t)l*8192, n_b1 + (size_t)l*64,
                    nw2f + (size_t)l*4096, n_b2 + (size_t)l*64,
                    nxt_f, nxt_b, Pb, Qb);
        }
        hipMemcpyAsync(x_new, x_old, (size_t)NN*3*sizeof(float),
                       hipMemcpyDeviceToDevice, stream);
        k_coord<<<eb, th, 0, stream>>>(Pb, Qb, radp, d0S, rowS, colS,
                q_w1 + (size_t)b*130*64 + 128*64,
                wf + (size_t)(4 + b)*4096,
                q_b2 + (size_t)b*64, q_w3 + (size_t)b*64, x_old, x_new);
    }
    k_out<<<nb, th, 0, stream>>>(h64, out_w, out_b, out_h);
}

// Round 9
// 655.766 us; speedup vs baseline: 3.2262x; 1.2794x over previous
//
#include <hip/hip_runtime.h>

#define NN 50000
#define NE 800000
#define NB 196   // (NN+255)/256

typedef unsigned int  u32;
typedef unsigned short u16;
typedef __attribute__((ext_vector_type(8))) short short8;
typedef __attribute__((ext_vector_type(4))) float f32x4;

union ABfrag { uint2 u2[2]; uint4 u4; short8 s8; };

__device__ __forceinline__ float silu_f(float v) {
    return v * __builtin_amdgcn_rcpf(1.0f + __expf(-v));
}
// cheap bf16 pair pack (round-half-up): 2 adds + 1 v_perm
__device__ __forceinline__ u32 pk2(float lo, float hi) {
    return __builtin_amdgcn_perm(__float_as_uint(hi) + 0x8000u,
                                 __float_as_uint(lo) + 0x8000u, 0x07060302u);
}
__device__ __forceinline__ float bff(u32 h) { return __uint_as_float(h << 16); }

// ---------------- embedding: h64 = h @ emb_w + emb_b  (N x 16 -> N x 64)
__global__ __launch_bounds__(256, 4) void k_embed(const float* __restrict__ h,
        const float* __restrict__ w, const float* __restrict__ b,
        float* __restrict__ h64) {
    int n = blockIdx.x * 256 + threadIdx.x;
    if (n >= NN) return;
    const float4* h4 = (const float4*)(h + (long)n * 16);
    float in[16];
    #pragma unroll
    for (int c = 0; c < 4; ++c) {
        float4 v = h4[c];
        in[4*c+0] = v.x; in[4*c+1] = v.y; in[4*c+2] = v.z; in[4*c+3] = v.w;
    }
    float acc[64];
    #pragma unroll
    for (int j = 0; j < 64; ++j) acc[j] = b[j];
    #pragma unroll
    for (int k = 0; k < 16; ++k) {
        #pragma unroll
        for (int j = 0; j < 64; ++j) acc[j] = fmaf(in[k], w[k*64 + j], acc[j]);
    }
    float4* o4 = (float4*)(h64 + (long)n * 64);
    #pragma unroll
    for (int c = 0; c < 16; ++c)
        o4[c] = make_float4(acc[4*c+0], acc[4*c+1], acc[4*c+2], acc[4*c+3]);
}

// ---------------- CSR-order build ----------------
__global__ __launch_bounds__(256, 4) void k_hist(const int* __restrict__ row,
        int* __restrict__ deg) {
    int e = blockIdx.x * 256 + threadIdx.x;
    if (e < NE) atomicAdd(&deg[row[e]], 1);
}

// stage A: per-block sums
__global__ __launch_bounds__(256, 4) void k_scanA(const int* __restrict__ deg,
        int* __restrict__ bsum) {
    int t = threadIdx.x, i = blockIdx.x * 256 + t;
    int v = (i < NN) ? deg[i] : 0;
    #pragma unroll
    for (int d = 1; d < 64; d <<= 1) v += __shfl_xor(v, d);
    __shared__ int ws[4];
    if ((t & 63) == 0) ws[t >> 6] = v;
    __syncthreads();
    if (t == 0) bsum[blockIdx.x] = ws[0] + ws[1] + ws[2] + ws[3];
}

// stage B: scan the NB block sums (1 block)
__global__ __launch_bounds__(256) void k_scanB(const int* __restrict__ bsum,
        int* __restrict__ bpre) {
    __shared__ int s[256];
    int t = threadIdx.x;
    int v = (t < NB) ? bsum[t] : 0;
    s[t] = v;
    __syncthreads();
    #pragma unroll
    for (int d = 1; d < 256; d <<= 1) {
        int u = (t >= d) ? s[t - d] : 0;
        __syncthreads();
        s[t] += u;
        __syncthreads();
    }
    if (t < NB) bpre[t] = s[t] - v;   // exclusive prefix of block sums
}

// stage C: intra-block exclusive scan + block offset
__global__ __launch_bounds__(256, 4) void k_scanC(const int* __restrict__ deg,
        const int* __restrict__ bpre, int* __restrict__ base) {
    int t = threadIdx.x, i = blockIdx.x * 256 + t;
    int lane = t & 63, w = t >> 6;
    int v = (i < NN) ? deg[i] : 0;
    int x = v;
    #pragma unroll
    for (int d = 1; d < 64; d <<= 1) {
        int u = __shfl_up(x, d);
        if (lane >= d) x += u;
    }
    __shared__ int wsum[4];
    if (lane == 63) wsum[w] = x;
    __syncthreads();
    int off = bpre[blockIdx.x];
    #pragma unroll
    for (int ww = 0; ww < 3; ++ww) if (ww < w) off += wsum[ww];
    if (i < NN) base[i] = off + x - v;   // exclusive
}

__global__ __launch_bounds__(256, 4) void k_scatter(const int* __restrict__ row,
        const int* __restrict__ col, int* __restrict__ base,
        int* __restrict__ rowS, int* __restrict__ colS) {
    int e = blockIdx.x * 256 + threadIdx.x;
    if (e >= NE) return;
    int r = row[e];
    int p = atomicAdd(&base[r], 1);
    rowS[p] = r;
    colS[p] = col[e];
}

// ---------------- per-edge squared distance (sorted edge space)
__global__ __launch_bounds__(256, 4) void k_radial(const float* __restrict__ x,
        const int* __restrict__ rowS, const int* __restrict__ colS,
        float* __restrict__ radial) {
    int e = blockIdx.x * 256 + threadIdx.x;
    if (e >= NE) return;
    int r = rowS[e], c = colS[e];
    float dx = x[r*3+0] - x[c*3+0];
    float dy = x[r*3+1] - x[c*3+1];
    float dz = x[r*3+2] - x[c*3+2];
    radial[e] = dx*dx + dy*dy + dz*dz;
}

// ---------------- weight -> bf16 B-fragment tables (RNE, one-time)
__device__ __forceinline__ u32 bfr_rne(float x) {
    u32 u = __float_as_uint(x);
    u += 0x7fffu + ((u >> 16) & 1u);
    return u >> 16;
}
__global__ __launch_bounds__(256, 4) void k_wconv(const float* __restrict__ e_w2,
        const float* __restrict__ q_w2, const float* __restrict__ n_w1,
        const float* __restrict__ n_w2, const float* __restrict__ e_w1,
        const float* __restrict__ q_w1, u16* __restrict__ wf) {
    int t = blockIdx.x * 256 + threadIdx.x;
    if (t >= 122880) return;
    int j, lane, n, s, k, col;
    if (t < 24576) {
        int L = t >> 12, v = t & 4095;
        j = v & 7; lane = (v >> 3) & 63; int ns = v >> 9; n = ns >> 1; s = ns & 1;
        k = 8*(lane >> 4) + j + 32*s;
        col = 16*n + (lane & 15);
        const float* src = (L < 4) ? e_w2 + (size_t)L*4096 : q_w2 + (size_t)(L-4)*4096;
        wf[t] = (u16)bfr_rne(src[k*64 + col]);
    } else if (t < 57344) {
        int u = t - 24576; int L = u >> 13, v = u & 8191;
        j = v & 7; lane = (v >> 3) & 63; int ns = v >> 9; n = ns >> 2; s = ns & 3;
        k = 8*(lane >> 4) + j + 32*s;
        col = 16*n + (lane & 15);
        wf[t] = (u16)bfr_rne(n_w1[(size_t)L*8192 + k*64 + col]);
    } else if (t < 73728) {
        int u = t - 57344; int L = u >> 12, v = u & 4095;
        j = v & 7; lane = (v >> 3) & 63; int ns = v >> 9; n = ns >> 1; s = ns & 1;
        k = 8*(lane >> 4) + j + 32*s;
        col = 16*n + (lane & 15);
        wf[t] = (u16)bfr_rne(n_w2[(size_t)L*4096 + k*64 + col]);
    } else {
        int u = t - 73728;
        int L = u >> 13;
        int v = u & 8191;
        int m = v >> 12;
        int v2 = v & 4095;
        j = v2 & 7; lane = (v2 >> 3) & 63; int ns = v2 >> 9; n = ns >> 1; s = ns & 1;
        k = 8*(lane >> 4) + j + 32*s;
        col = 16*n + (lane & 15);
        const float* src = (L < 4) ? e_w1 + (size_t)L*130*64
                                   : q_w1 + (size_t)(L-4)*130*64;
        wf[t] = (u16)bfr_rne(src[(size_t)(m*64 + k)*64 + col]);
    }
}

// ---------------- standalone P/Q via MFMA (layers l0, l2 only)
__global__ __launch_bounds__(256, 4) void k_pq(const float* __restrict__ h64,
        const u16* __restrict__ wpf, const float* __restrict__ b1,
        u32* __restrict__ Pb, u32* __restrict__ Qb) {
    __shared__ u16 A[64*64];
    __shared__ u16 XP[64*68], XQ[64*68];
    int t = threadIdx.x, w = t >> 6, lane = t & 63;
    int nb0 = blockIdx.x * 64;
    #pragma unroll
    for (int i = 0; i < 4; ++i) {
        int idx = i*256 + t;
        int r = idx >> 4, c = idx & 15;
        int n = nb0 + r;
        float4 v = make_float4(0.f, 0.f, 0.f, 0.f);
        if (n < NN) v = ((const float4*)(h64 + (size_t)n*64))[c];
        uint2 pk = make_uint2(pk2(v.x, v.y), pk2(v.z, v.w));
        *(uint2*)((char*)A + r*128 + ((8*c) ^ ((r & 15) << 3))) = pk;
    }
    __syncthreads();
    int r0 = lane & 15, g = lane >> 4;
    ABfrag bp[2], bq[2];
    #pragma unroll
    for (int s = 0; s < 2; ++s) {
        bp[s].u4 = *(const uint4*)(wpf + ((size_t)(w*2 + s)*64 + lane)*8);
        bq[s].u4 = *(const uint4*)(wpf + 4096 + ((size_t)(w*2 + s)*64 + lane)*8);
    }
    f32x4 aP[4], aQ[4];
    #pragma unroll
    for (int t4 = 0; t4 < 4; ++t4) {
        aP[t4] = (f32x4){0.f, 0.f, 0.f, 0.f};
        aQ[t4] = (f32x4){0.f, 0.f, 0.f, 0.f};
    }
    #pragma unroll
    for (int t4 = 0; t4 < 4; ++t4) {
        #pragma unroll
        for (int s = 0; s < 2; ++s) {
            int boff = 16*g + 64*s;
            ABfrag af;
            af.u2[0] = *(uint2*)((char*)A + (16*t4 + r0)*128 + ( boff      ^ (r0 << 3)));
            af.u2[1] = *(uint2*)((char*)A + (16*t4 + r0)*128 + ((boff + 8) ^ (r0 << 3)));
            aP[t4] = __builtin_amdgcn_mfma_f32_16x16x32_bf16(af.s8, bp[s].s8, aP[t4], 0, 0, 0);
            aQ[t4] = __builtin_amdgcn_mfma_f32_16x16x32_bf16(af.s8, bq[s].s8, aQ[t4], 0, 0, 0);
        }
    }
    float bv = b1[16*w + r0];
    #pragma unroll
    for (int t4 = 0; t4 < 4; ++t4)
        #pragma unroll
        for (int q = 0; q < 4; ++q) {
            int rw = 16*t4 + 4*g + q;
            XP[rw*68 + 16*w + r0] = (u16)(pk2(aP[t4][q] + bv, 0.f) & 0xffffu);
            XQ[rw*68 + 16*w + r0] = (u16)(pk2(aQ[t4][q], 0.f) & 0xffffu);
        }
    __syncthreads();
    int node = t >> 2, part = t & 3;
    if (nb0 + node < NN) {
        const u32* XPw = (const u32*)XP;
        const u32* XQw = (const u32*)XQ;
        u32 b[8];
        #pragma unroll
        for (int j = 0; j < 8; ++j) b[j] = XPw[node*34 + 8*part + j];
        uint4* dp = (uint4*)(Pb + (size_t)(nb0 + node)*32 + part*8);
        dp[0] = make_uint4(b[0], b[1], b[2], b[3]);
        dp[1] = make_uint4(b[4], b[5], b[6], b[7]);
        #pragma unroll
        for (int j = 0; j < 8; ++j) b[j] = XQw[node*34 + 8*part + j];
        uint4* dq = (uint4*)(Qb + (size_t)(nb0 + node)*32 + part*8);
        dq[0] = make_uint4(b[0], b[1], b[2], b[3]);
        dq[1] = make_uint4(b[4], b[5], b[6], b[7]);
    }
}

// ---------------- edge MLP: uint4 gathers, pk2 packs, ballot/readlane agg
__global__ __launch_bounds__(256, 4) void k_edge(
        const u32* __restrict__ Pb, const u32* __restrict__ Qb,
        const float* __restrict__ radial, const float* __restrict__ dist0,
        const int* __restrict__ rowS, const int* __restrict__ colS,
        const float* __restrict__ w1t, const u16* __restrict__ w2f,
        const float* __restrict__ b2, float* __restrict__ agg) {
    __shared__ u16 S_lds[4][4224];   // union: A [64][64] / M [64f][66e]
    int tid = threadIdx.x;
    int w = tid >> 6, lane = tid & 63;
    int e = blockIdx.x * 256 + w * 64 + lane;
    u16* Aw = S_lds[w];
    int r = rowS[e], c = colS[e];
    float rad = radial[e], d0 = dist0[e];
    const uint4* Pr = (const uint4*)(Pb + (size_t)r * 32);
    const uint4* Qc = (const uint4*)(Qb + (size_t)c * 32);
    int swz = (lane & 15) << 3;
    #pragma unroll
    for (int c8 = 0; c8 < 8; ++c8) {
        uint4 pu = Pr[c8], qu = Qc[c8];
        u32 pw[4] = {pu.x, pu.y, pu.z, pu.w};
        u32 qw[4] = {qu.x, qu.y, qu.z, qu.w};
        float hv[8];
        #pragma unroll
        for (int k2 = 0; k2 < 4; ++k2) {
            int f = 8*c8 + 2*k2;
            float pl = bff(pw[k2] & 0xffffu), ph = bff(pw[k2] >> 16);
            float ql = bff(qw[k2] & 0xffffu), qh = bff(qw[k2] >> 16);
            hv[2*k2]   = silu_f(pl + ql + rad*w1t[f]     + d0*w1t[64+f]);
            hv[2*k2+1] = silu_f(ph + qh + rad*w1t[f+1]   + d0*w1t[64+f+1]);
        }
        uint2 pkA = make_uint2(pk2(hv[0], hv[1]), pk2(hv[2], hv[3]));
        uint2 pkB = make_uint2(pk2(hv[4], hv[5]), pk2(hv[6], hv[7]));
        *(uint2*)((char*)Aw + lane*128 + ((16*c8)     ^ swz)) = pkA;
        *(uint2*)((char*)Aw + lane*128 + ((16*c8 + 8) ^ swz)) = pkB;
    }
    __syncthreads();
    ABfrag bf[4][2];
    #pragma unroll
    for (int n = 0; n < 4; ++n)
        #pragma unroll
        for (int s = 0; s < 2; ++s)
            bf[n][s].u4 = *(const uint4*)(w2f + ((n*2 + s)*64 + lane)*8);
    int r0 = lane & 15, g = lane >> 4;
    f32x4 acc[4][4];
    #pragma unroll
    for (int t = 0; t < 4; ++t)
        #pragma unroll
        for (int n = 0; n < 4; ++n)
            acc[t][n] = (f32x4){0.f, 0.f, 0.f, 0.f};
    #pragma unroll
    for (int t = 0; t < 4; ++t) {
        #pragma unroll
        for (int s = 0; s < 2; ++s) {
            int boff = 16*g + 64*s;
            ABfrag af;
            af.u2[0] = *(uint2*)((char*)Aw + (16*t + r0)*128 + ( boff      ^ (r0 << 3)));
            af.u2[1] = *(uint2*)((char*)Aw + (16*t + r0)*128 + ((boff + 8) ^ (r0 << 3)));
            #pragma unroll
            for (int n = 0; n < 4; ++n)
                acc[t][n] = __builtin_amdgcn_mfma_f32_16x16x32_bf16(
                    af.s8, bf[n][s].s8, acc[t][n], 0, 0, 0);
        }
    }
    __syncthreads();
    u16* Mw = Aw;      // overlay: [64 feat][66 edge], row stride 132 B
    #pragma unroll
    for (int n = 0; n < 4; ++n) {
        float b2v = b2[16*n + r0];
        #pragma unroll
        for (int t = 0; t < 4; ++t) {
            f32x4 z = acc[t][n];
            u32 p0 = pk2(silu_f(z[0] + b2v), silu_f(z[1] + b2v));
            u32 p1 = pk2(silu_f(z[2] + b2v), silu_f(z[3] + b2v));
            *(uint2*)((char*)Mw + (16*n + r0)*132 + 32*t + 8*g) = make_uint2(p0, p1);
        }
    }
    __syncthreads();
    int rnext = __shfl_down(r, 1);
    unsigned long long tm = __ballot((lane == 63) || (rnext != r));
    float racc = 0.0f;
    #pragma unroll
    for (int ch = 0; ch < 16; ++ch) {
        uint2 mm = *(uint2*)((char*)Mw + lane*132 + 8*ch);
        u32 mw[2] = {mm.x, mm.y};
        #pragma unroll
        for (int q = 0; q < 4; ++q) {
            int ee = 4*ch + q;
            racc += bff((mw[q >> 1] >> ((q & 1) * 16)) & 0xffffu);
            if ((tm >> ee) & 1ull) {
                int rr = __builtin_amdgcn_readlane(r, ee);
                atomicAdd(&agg[(size_t)rr*64 + lane], racc);
                racc = 0.0f;
            }
        }
    }
}

// ---------------- fused node MLP + next-layer P/Q (all MFMA)
__global__ __launch_bounds__(256, 3) void k_node_pq(float* __restrict__ h64,
        const float* __restrict__ agg,
        const u16* __restrict__ w1f, const float* __restrict__ b1,
        const u16* __restrict__ w2f, const float* __restrict__ b2,
        const u16* __restrict__ wpf, const float* __restrict__ b1pq,
        u32* __restrict__ Pb, u32* __restrict__ Qb) {
    __shared__ u16 S[16512];
    u16* A0 = S;
    u16* A1 = S + 4096;
    u16* H  = S + 8192;
    u16* D  = S + 12288;
    u16* An = S;
    u16* XPh = S + 4096;
    u16* XQh = S + 8448;
    int t = threadIdx.x, w = t >> 6, lane = t & 63;
    int nb0 = blockIdx.x * 64;
    #pragma unroll
    for (int i = 0; i < 8; ++i) {
        int idx = i*256 + t;
        int r = idx >> 5, c = idx & 31;
        int n = nb0 + r;
        float4 v = make_float4(0.f, 0.f, 0.f, 0.f);
        if (n < NN) {
            if (c < 16) v = ((const float4*)(h64 + (size_t)n*64))[c];
            else {
                float4 a = ((const float4*)(agg + (size_t)n*64))[c-16];
                v = make_float4(a.x*0.01f, a.y*0.01f, a.z*0.01f, a.w*0.01f);
            }
        }
        uint2 pk = make_uint2(pk2(v.x, v.y), pk2(v.z, v.w));
        u16* dst = (c < 16) ? A0 : A1;
        int cc = c & 15;
        *(uint2*)((char*)dst + r*128 + ((8*cc) ^ ((r & 15) << 3))) = pk;
    }
    __syncthreads();
    int r0 = lane & 15, g = lane >> 4;
    ABfrag bf1[4];
    #pragma unroll
    for (int s = 0; s < 4; ++s)
        bf1[s].u4 = *(const uint4*)(w1f + ((size_t)(w*4 + s)*64 + lane)*8);
    f32x4 acc[4];
    #pragma unroll
    for (int t4 = 0; t4 < 4; ++t4) acc[t4] = (f32x4){0.f, 0.f, 0.f, 0.f};
    #pragma unroll
    for (int t4 = 0; t4 < 4; ++t4) {
        #pragma unroll
        for (int s = 0; s < 4; ++s) {
            const u16* Ah = (s < 2) ? A0 : A1;
            int boff = 16*g + 64*(s & 1);
            ABfrag af;
            af.u2[0] = *(uint2*)((char*)Ah + (16*t4 + r0)*128 + ( boff      ^ (r0 << 3)));
            af.u2[1] = *(uint2*)((char*)Ah + (16*t4 + r0)*128 + ((boff + 8) ^ (r0 << 3)));
            acc[t4] = __builtin_amdgcn_mfma_f32_16x16x32_bf16(
                af.s8, bf1[s].s8, acc[t4], 0, 0, 0);
        }
    }
    float b1v = b1[16*w + r0];
    #pragma unroll
    for (int t4 = 0; t4 < 4; ++t4)
        #pragma unroll
        for (int q = 0; q < 4; ++q) {
            int rw = 16*t4 + 4*g + q;
            u16 hv = (u16)(pk2(silu_f(acc[t4][q] + b1v), 0.f) & 0xffffu);
            *(u16*)((char*)H + rw*128 + ((2*(16*w + r0)) ^ ((rw & 15) << 3))) = hv;
        }
    __syncthreads();
    ABfrag bf2[2];
    #pragma unroll
    for (int s = 0; s < 2; ++s)
        bf2[s].u4 = *(const uint4*)(w2f + ((size_t)(w*2 + s)*64 + lane)*8);
    f32x4 acc2[4];
    #pragma unroll
    for (int t4 = 0; t4 < 4; ++t4) acc2[t4] = (f32x4){0.f, 0.f, 0.f, 0.f};
    #pragma unroll
    for (int t4 = 0; t4 < 4; ++t4) {
        #pragma unroll
        for (int s = 0; s < 2; ++s) {
            int boff = 16*g + 64*s;
            ABfrag af;
            af.u2[0] = *(uint2*)((char*)H + (16*t4 + r0)*128 + ( boff      ^ (r0 << 3)));
            af.u2[1] = *(uint2*)((char*)H + (16*t4 + r0)*128 + ((boff + 8) ^ (r0 << 3)));
            acc2[t4] = __builtin_amdgcn_mfma_f32_16x16x32_bf16(
                af.s8, bf2[s].s8, acc2[t4], 0, 0, 0);
        }
    }
    float b2v = b2[16*w + r0];
    #pragma unroll
    for (int t4 = 0; t4 < 4; ++t4)
        #pragma unroll
        for (int q = 0; q < 4; ++q) {
            int rw = 16*t4 + 4*g + q;
            D[rw*66 + 16*w + r0] = (u16)(pk2(acc2[t4][q] + b2v, 0.f) & 0xffffu);
        }
    __syncthreads();
    #pragma unroll
    for (int i = 0; i < 4; ++i) {
        int idx = i*256 + t;
        int rr = idx >> 4, cc = idx & 15;
        int n = nb0 + rr;
        float4 v = make_float4(0.f, 0.f, 0.f, 0.f);
        if (n < NN) {
            v = ((const float4*)(h64 + (size_t)n*64))[cc];
            v.x += bff(D[rr*66 + 4*cc + 0]);
            v.y += bff(D[rr*66 + 4*cc + 1]);
            v.z += bff(D[rr*66 + 4*cc + 2]);
            v.w += bff(D[rr*66 + 4*cc + 3]);
            ((float4*)(h64 + (size_t)n*64))[cc] = v;
        }
        uint2 pk = make_uint2(pk2(v.x, v.y), pk2(v.z, v.w));
        *(uint2*)((char*)An + rr*128 + ((8*cc) ^ ((rr & 15) << 3))) = pk;
    }
    __syncthreads();
    ABfrag bp[2], bq[2];
    #pragma unroll
    for (int s = 0; s < 2; ++s) {
        bp[s].u4 = *(const uint4*)(wpf + ((size_t)(w*2 + s)*64 + lane)*8);
        bq[s].u4 = *(const uint4*)(wpf + 4096 + ((size_t)(w*2 + s)*64 + lane)*8);
    }
    f32x4 aP[4], aQ[4];
    #pragma unroll
    for (int t4 = 0; t4 < 4; ++t4) {
        aP[t4] = (f32x4){0.f, 0.f, 0.f, 0.f};
        aQ[t4] = (f32x4){0.f, 0.f, 0.f, 0.f};
    }
    #pragma unroll
    for (int t4 = 0; t4 < 4; ++t4) {
        #pragma unroll
        for (int s = 0; s < 2; ++s) {
            int boff = 16*g + 64*s;
            ABfrag af;
            af.u2[0] = *(uint2*)((char*)An + (16*t4 + r0)*128 + ( boff      ^ (r0 << 3)));
            af.u2[1] = *(uint2*)((char*)An + (16*t4 + r0)*128 + ((boff + 8) ^ (r0 << 3)));
            aP[t4] = __builtin_amdgcn_mfma_f32_16x16x32_bf16(af.s8, bp[s].s8, aP[t4], 0, 0, 0);
            aQ[t4] = __builtin_amdgcn_mfma_f32_16x16x32_bf16(af.s8, bq[s].s8, aQ[t4], 0, 0, 0);
        }
    }
    float bv = b1pq[16*w + r0];
    #pragma unroll
    for (int t4 = 0; t4 < 4; ++t4)
        #pragma unroll
        for (int q = 0; q < 4; ++q) {
            int rw = 16*t4 + 4*g + q;
            XPh[rw*68 + 16*w + r0] = (u16)(pk2(aP[t4][q] + bv, 0.f) & 0xffffu);
            XQh[rw*68 + 16*w + r0] = (u16)(pk2(aQ[t4][q], 0.f) & 0xffffu);
        }
    __syncthreads();
    int node = t >> 2, part = t & 3;
    if (nb0 + node < NN) {
        const u32* XPw = (const u32*)XPh;
        const u32* XQw = (const u32*)XQh;
        u32 b[8];
        #pragma unroll
        for (int j = 0; j < 8; ++j) b[j] = XPw[node*34 + 8*part + j];
        uint4* dp = (uint4*)(Pb + (size_t)(nb0 + node)*32 + part*8);
        dp[0] = make_uint4(b[0], b[1], b[2], b[3]);
        dp[1] = make_uint4(b[4], b[5], b[6], b[7]);
        #pragma unroll
        for (int j = 0; j < 8; ++j) b[j] = XQw[node*34 + 8*part + j];
        uint4* dq = (uint4*)(Qb + (size_t)(nb0 + node)*32 + part*8);
        dq[0] = make_uint4(b[0], b[1], b[2], b[3]);
        dq[1] = make_uint4(b[4], b[5], b[6], b[7]);
    }
}

// ---------------- coordinate update: MFMA layer2, LDS phi reduction
__global__ __launch_bounds__(256, 4) void k_coord(
        const u32* __restrict__ Pb, const u32* __restrict__ Qb,
        const float* __restrict__ radial, const float* __restrict__ dist0,
        const int* __restrict__ rowS, const int* __restrict__ colS,
        const float* __restrict__ w1t, const u16* __restrict__ w2f,
        const float* __restrict__ b2, const float* __restrict__ w3,
        const float* __restrict__ x_old, float* __restrict__ x_new) {
    __shared__ u16 A_lds[4][4096];
    int tid = threadIdx.x;
    int w = tid >> 6, lane = tid & 63;
    int e = blockIdx.x * 256 + w * 64 + lane;
    u16* Aw = A_lds[w];
    int r = rowS[e], c = colS[e];
    float rad = radial[e], d0 = dist0[e];
    const uint4* Pr = (const uint4*)(Pb + (size_t)r * 32);
    const uint4* Qc = (const uint4*)(Qb + (size_t)c * 32);
    int swz = (lane & 15) << 3;
    #pragma unroll
    for (int c8 = 0; c8 < 8; ++c8) {
        uint4 pu = Pr[c8], qu = Qc[c8];
        u32 pw[4] = {pu.x, pu.y, pu.z, pu.w};
        u32 qw[4] = {qu.x, qu.y, qu.z, qu.w};
        float hv[8];
        #pragma unroll
        for (int k2 = 0; k2 < 4; ++k2) {
            int f = 8*c8 + 2*k2;
            float pl = bff(pw[k2] & 0xffffu), ph = bff(pw[k2] >> 16);
            float ql = bff(qw[k2] & 0xffffu), qh = bff(qw[k2] >> 16);
            hv[2*k2]   = silu_f(pl + ql + rad*w1t[f]   + d0*w1t[64+f]);
            hv[2*k2+1] = silu_f(ph + qh + rad*w1t[f+1] + d0*w1t[64+f+1]);
        }
        uint2 pkA = make_uint2(pk2(hv[0], hv[1]), pk2(hv[2], hv[3]));
        uint2 pkB = make_uint2(pk2(hv[4], hv[5]), pk2(hv[6], hv[7]));
        *(uint2*)((char*)Aw + lane*128 + ((16*c8)     ^ swz)) = pkA;
        *(uint2*)((char*)Aw + lane*128 + ((16*c8 + 8) ^ swz)) = pkB;
    }
    __syncthreads();
    ABfrag bf[4][2];
    #pragma unroll
    for (int n = 0; n < 4; ++n)
        #pragma unroll
        for (int s = 0; s < 2; ++s)
            bf[n][s].u4 = *(const uint4*)(w2f + ((n*2 + s)*64 + lane)*8);
    int r0 = lane & 15, g = lane >> 4;
    f32x4 acc[4][4];
    #pragma unroll
    for (int t = 0; t < 4; ++t)
        #pragma unroll
        for (int n = 0; n < 4; ++n)
            acc[t][n] = (f32x4){0.f, 0.f, 0.f, 0.f};
    #pragma unroll
    for (int t = 0; t < 4; ++t) {
        #pragma unroll
        for (int s = 0; s < 2; ++s) {
            int boff = 16*g + 64*s;
            ABfrag af;
            af.u2[0] = *(uint2*)((char*)Aw + (16*t + r0)*128 + ( boff      ^ (r0 << 3)));
            af.u2[1] = *(uint2*)((char*)Aw + (16*t + r0)*128 + ((boff + 8) ^ (r0 << 3)));
            #pragma unroll
            for (int n = 0; n < 4; ++n)
                acc[t][n] = __builtin_amdgcn_mfma_f32_16x16x32_bf16(
                    af.s8, bf[n][s].s8, acc[t][n], 0, 0, 0);
        }
    }
    float w3v[4], b2v[4];
    #pragma unroll
    for (int n = 0; n < 4; ++n) { w3v[n] = w3[16*n + r0]; b2v[n] = b2[16*n + r0]; }
    float ph[16];
    #pragma unroll
    for (int t = 0; t < 4; ++t)
        #pragma unroll
        for (int q = 0; q < 4; ++q) {
            float s = 0.f;
            #pragma unroll
            for (int n = 0; n < 4; ++n)
                s = fmaf(silu_f(acc[t][n][q] + b2v[n]), w3v[n], s);
            ph[t*4 + q] = s;
        }
    __syncthreads();
    float* Mw = (float*)Aw;
    #pragma unroll
    for (int t4 = 0; t4 < 4; ++t4)
        #pragma unroll
        for (int q = 0; q < 4; ++q)
            Mw[(16*t4 + 4*g + q)*17 + r0] = ph[t4*4 + q];
    __syncthreads();
    float phi = 0.f;
    #pragma unroll
    for (int i = 0; i < 16; ++i) phi += Mw[lane*17 + i];
    phi *= 0.01f;
    float dx = x_old[r*3+0] - x_old[c*3+0];
    float dy = x_old[r*3+1] - x_old[c*3+1];
    float dz = x_old[r*3+2] - x_old[c*3+2];
    float inv = phi / (sqrtf(rad + 1e-8f) + 1.0f);
    float tx = dx * inv, ty = dy * inv, tz = dz * inv;
    int rprev = __shfl_up(r, 1);
    bool head = (lane == 0) || (rprev != r);
    unsigned long long hm = __ballot(head);
    int runid = __popcll(hm & ((2ull << lane) - 1ull));
    #pragma unroll
    for (int d = 1; d < 64; d <<= 1) {
        float ox = __shfl_up(tx, d);
        float oy = __shfl_up(ty, d);
        float oz = __shfl_up(tz, d);
        int orid = __shfl_up(runid, d);
        if (lane >= d && orid == runid) { tx += ox; ty += oy; tz += oz; }
    }
    int rid_next = __shfl_down(runid, 1);
    bool tail = (lane == 63) || (rid_next != runid);
    if (tail) {
        atomicAdd(&x_new[r*3+0], tx);
        atomicAdd(&x_new[r*3+1], ty);
        atomicAdd(&x_new[r*3+2], tz);
    }
}

// ---------------- output projection
__global__ __launch_bounds__(256, 4) void k_out(const float* __restrict__ h64,
        const float* __restrict__ w, const float* __restrict__ b,
        float* __restrict__ out) {
    int n = blockIdx.x * 256 + threadIdx.x;
    if (n >= NN) return;
    float acc[16];
    #pragma unroll
    for (int j = 0; j < 16; ++j) acc[j] = b[j];
    const float4* h4 = (const float4*)(h64 + (long)n*64);
    #pragma unroll
    for (int c = 0; c < 16; ++c) {
        float4 v = h4[c];
        float vv[4] = {v.x, v.y, v.z, v.w};
        #pragma unroll
        for (int t = 0; t < 4; ++t) {
            #pragma unroll
            for (int j = 0; j < 16; ++j)
                acc[j] = fmaf(vv[t], w[(4*c+t)*16 + j], acc[j]);
        }
    }
    float4* o4 = (float4*)(out + (long)n*16);
    #pragma unroll
    for (int cq = 0; cq < 4; ++cq)
        o4[cq] = make_float4(acc[4*cq+0],acc[4*cq+1],acc[4*cq+2],acc[4*cq+3]);
}

extern "C" void kernel_launch(void* const* d_in, const int* in_sizes, int n_in,
                              void* d_out, int out_size, void* d_ws, size_t ws_size,
                              hipStream_t stream) {
    const float* h_in  = (const float*)d_in[0];
    const float* x_in  = (const float*)d_in[1];
    const int*   row   = (const int*)d_in[2];
    const int*   col   = (const int*)d_in[3];
    const float* emb_w = (const float*)d_in[4];
    const float* emb_b = (const float*)d_in[5];
    const float* out_w = (const float*)d_in[6];
    const float* out_b = (const float*)d_in[7];
    const float* e_w1  = (const float*)d_in[8];
    const float* e_b1  = (const float*)d_in[9];
    const float* e_w2  = (const float*)d_in[10];
    const float* e_b2  = (const float*)d_in[11];
    const float* n_w1  = (const float*)d_in[12];
    const float* n_b1  = (const float*)d_in[13];
    const float* n_w2  = (const float*)d_in[14];
    const float* n_b2  = (const float*)d_in[15];
    const float* q_w1  = (const float*)d_in[16];
    const float* q_b1  = (const float*)d_in[17];
    const float* q_w2  = (const float*)d_in[18];
    const float* q_b2  = (const float*)d_in[19];
    const float* q_w3  = (const float*)d_in[20];

    const size_t WF_N = 122880;
    const size_t WF_BYTES = WF_N * sizeof(u16);
    size_t need = WF_BYTES + ((size_t)NN*64*4 + (size_t)NE*2 + (size_t)NN*3
                   + (size_t)NE*2 + (size_t)NN*2 + 1024) * sizeof(float);
    if (ws_size < need) return;

    u16*   wf    = (u16*)d_ws;
    float* fb    = (float*)((char*)d_ws + WF_BYTES);
    float* h64   = fb;
    u32*   Pb    = (u32*)(h64 + (size_t)NN*64);
    u32*   Qb    = Pb + (size_t)NN*32;
    float* agg   = (float*)(Qb + (size_t)NN*32);
    float* d0S   = agg   + (size_t)NN*64;
    float* radS  = d0S   + (size_t)NE;
    float* xA    = radS  + (size_t)NE;
    int*   rowS  = (int*)(xA + (size_t)NN*3);
    int*   colS  = rowS  + (size_t)NE;
    int*   deg   = colS  + (size_t)NE;
    int*   base  = deg   + (size_t)NN;
    int*   bsum  = base  + (size_t)NN;   // NB
    int*   bpre  = bsum  + 256;          // NB

    float* out_h = (float*)d_out;
    float* out_x = out_h + (size_t)NN*16;

    dim3 th(256);
    dim3 nb((NN + 255)/256);
    dim3 eb(NE/256);
    dim3 t64b((NN + 63)/64);

    hipMemsetAsync(deg, 0, (size_t)NN*sizeof(int), stream);
    k_hist<<<eb, th, 0, stream>>>(row, deg);
    k_scanA<<<NB, th, 0, stream>>>(deg, bsum);
    k_scanB<<<1, th, 0, stream>>>(bsum, bpre);
    k_scanC<<<NB, th, 0, stream>>>(deg, bpre, base);
    k_scatter<<<eb, th, 0, stream>>>(row, col, base, rowS, colS);
    k_wconv<<<480, th, 0, stream>>>(e_w2, q_w2, n_w1, n_w2, e_w1, q_w1, wf);

    k_radial<<<eb, th, 0, stream>>>(x_in, rowS, colS, d0S);
    k_embed<<<nb, th, 0, stream>>>(h_in, emb_w, emb_b, h64);

    const u16* nw1f = wf + 24576;
    const u16* nw2f = wf + 57344;
    const u16* pqf  = wf + 73728;

    for (int b = 0; b < 2; ++b) {
        const float* x_old;
        float*       x_new;
        const float* radp;
        if (b == 0) {
            x_old = x_in;  x_new = xA;    radp = d0S;
        } else {
            x_old = xA;    x_new = out_x; radp = radS;
            k_radial<<<eb, th, 0, stream>>>(x_old, rowS, colS, radS);
        }
        for (int i = 0; i < 2; ++i) {
            int l = b*2 + i;
            if (i == 0)
                k_pq<<<t64b, th, 0, stream>>>(h64, pqf + (size_t)l*8192,
                                              e_b1 + (size_t)l*64, Pb, Qb);
            hipMemsetAsync(agg, 0, (size_t)NN*64*sizeof(float), stream);
            k_edge<<<eb, th, 0, stream>>>(Pb, Qb, radp, d0S, rowS, colS,
                    e_w1 + (size_t)l*130*64 + 128*64,
                    wf + (size_t)l*4096,
                    e_b2 + (size_t)l*64, agg);
            const u16* nxt_f  = (i == 0) ? pqf + (size_t)(l+1)*8192
                                         : pqf + (size_t)(4 + b)*8192;
            const float* nxt_b = (i == 0) ? e_b1 + (size_t)(l+1)*64
                                          : q_b1 + (size_t)b*64;
            k_node_pq<<<t64b, th, 0, stream>>>(h64, agg,
                    nw1f + (size_t)l*8192, n_b1 + (size_t)l*64,
                    nw2f + (size_t)l*4096, n_b2 + (size_t)l*64,
                    nxt_f, nxt_b, Pb, Qb);
        }
        hipMemcpyAsync(x_new, x_old, (size_t)NN*3*sizeof(float),
                       hipMemcpyDeviceToDevice, stream);
        k_coord<<<eb, th, 0, stream>>>(Pb, Qb, radp, d0S, rowS, colS,
                q_w1 + (size_t)b*130*64 + 128*64,
                wf + (size_t)(4 + b)*4096,
                q_b2 + (size_t)b*64, q_w3 + (size_t)b*64, x_old, x_new);
    }
    k_out<<<nb, th, 0, stream>>>(h64, out_w, out_b, out_h);
}